// Round 2
// baseline (587.618 us; speedup 1.0000x reference)
//
#include <hip/hip_runtime.h>
#include <math.h>

// Interaction Network:
//  K0: zero aggr
//  K1 (edges): e_msg = MLP_R1([x[dst], x[src], edge_attr]) ; aggr[dst] += e_msg
//  K2 (nodes): x_tilde = MLP_O([x, aggr])
//  K3 (edges): out = sigmoid(MLP_R2([x_tilde[dst], x_tilde[src], e_msg]))
// NOTE: harness delivers integer inputs as int32 (edge_index int64 -> int32).

template<int IN, int OUT, bool RELU>
__device__ __forceinline__ void dense(const float* __restrict__ w,
                                      const float* __restrict__ b,
                                      const float* in, float* out) {
#pragma unroll
    for (int j = 0; j < OUT; ++j) {
        float acc = b[j];
#pragma unroll
        for (int k = 0; k < IN; ++k) acc = fmaf(w[j * IN + k], in[k], acc);
        out[j] = RELU ? fmaxf(acc, 0.f) : acc;
    }
}

__global__ __launch_bounds__(256) void zero_kernel(float* __restrict__ p, int n) {
    int i = blockIdx.x * blockDim.x + threadIdx.x;
    if (i < n) p[i] = 0.f;
}

__device__ __forceinline__ void r1_forward(
    const float* __restrict__ x, const float* __restrict__ ea,
    int src, int dst, int e,
    const float* __restrict__ w1, const float* __restrict__ b1,
    const float* __restrict__ w2, const float* __restrict__ b2,
    const float* __restrict__ w3, const float* __restrict__ b3,
    float* m)
{
    float in[10];
    in[0] = x[dst * 3 + 0]; in[1] = x[dst * 3 + 1]; in[2] = x[dst * 3 + 2];
    in[3] = x[src * 3 + 0]; in[4] = x[src * 3 + 1]; in[5] = x[src * 3 + 2];
    float4 eav = *reinterpret_cast<const float4*>(ea + (size_t)e * 4);
    in[6] = eav.x; in[7] = eav.y; in[8] = eav.z; in[9] = eav.w;

    float h1[40], h2[40];
    dense<10, 40, true >(w1, b1, in, h1);
    dense<40, 40, true >(w2, b2, h1, h2);
    dense<40, 4,  false>(w3, b3, h2, m);
}

template<bool STORE_MSG>
__global__ __launch_bounds__(256) void msg_kernel(
    const float* __restrict__ x,
    const int* __restrict__ ei,
    const float* __restrict__ ea,
    const float* __restrict__ w1, const float* __restrict__ b1,
    const float* __restrict__ w2, const float* __restrict__ b2,
    const float* __restrict__ w3, const float* __restrict__ b3,
    float* __restrict__ e_msg, float* __restrict__ aggr,
    int n_edges)
{
    int e = blockIdx.x * blockDim.x + threadIdx.x;
    if (e >= n_edges) return;
    int src = ei[e];
    int dst = ei[n_edges + e];

    float m[4];
    r1_forward(x, ea, src, dst, e, w1, b1, w2, b2, w3, b3, m);

    if (STORE_MSG)
        *reinterpret_cast<float4*>(e_msg + (size_t)e * 4) = make_float4(m[0], m[1], m[2], m[3]);
    atomicAdd(&aggr[dst * 4 + 0], m[0]);
    atomicAdd(&aggr[dst * 4 + 1], m[1]);
    atomicAdd(&aggr[dst * 4 + 2], m[2]);
    atomicAdd(&aggr[dst * 4 + 3], m[3]);
}

__global__ __launch_bounds__(256) void node_kernel(
    const float* __restrict__ x,
    const float* __restrict__ aggr,
    const float* __restrict__ w1, const float* __restrict__ b1,
    const float* __restrict__ w2, const float* __restrict__ b2,
    const float* __restrict__ w3, const float* __restrict__ b3,
    float* __restrict__ xt,
    int n_nodes)
{
    int n = blockIdx.x * blockDim.x + threadIdx.x;
    if (n >= n_nodes) return;

    float in[7];
    in[0] = x[n * 3 + 0]; in[1] = x[n * 3 + 1]; in[2] = x[n * 3 + 2];
    float4 ag = *reinterpret_cast<const float4*>(aggr + (size_t)n * 4);
    in[3] = ag.x; in[4] = ag.y; in[5] = ag.z; in[6] = ag.w;

    float h1[40], h2[40], o[3];
    dense<7, 40, true >(w1, b1, in, h1);
    dense<40, 40, true>(w2, b2, h1, h2);
    dense<40, 3, false>(w3, b3, h2, o);

    xt[n * 3 + 0] = o[0]; xt[n * 3 + 1] = o[1]; xt[n * 3 + 2] = o[2];
}

template<bool LOAD_MSG>
__global__ __launch_bounds__(256) void out_kernel(
    const float* __restrict__ xt,
    const int* __restrict__ ei,
    const float* __restrict__ e_msg,
    // recompute path inputs:
    const float* __restrict__ x,
    const float* __restrict__ ea,
    const float* __restrict__ r1w1, const float* __restrict__ r1b1,
    const float* __restrict__ r1w2, const float* __restrict__ r1b2,
    const float* __restrict__ r1w3, const float* __restrict__ r1b3,
    // R2 weights:
    const float* __restrict__ w1, const float* __restrict__ b1,
    const float* __restrict__ w2, const float* __restrict__ b2,
    const float* __restrict__ w3, const float* __restrict__ b3,
    float* __restrict__ out,
    int n_edges)
{
    int e = blockIdx.x * blockDim.x + threadIdx.x;
    if (e >= n_edges) return;
    int src = ei[e];
    int dst = ei[n_edges + e];

    float in[10];
    in[0] = xt[dst * 3 + 0]; in[1] = xt[dst * 3 + 1]; in[2] = xt[dst * 3 + 2];
    in[3] = xt[src * 3 + 0]; in[4] = xt[src * 3 + 1]; in[5] = xt[src * 3 + 2];
    if (LOAD_MSG) {
        float4 mv = *reinterpret_cast<const float4*>(e_msg + (size_t)e * 4);
        in[6] = mv.x; in[7] = mv.y; in[8] = mv.z; in[9] = mv.w;
    } else {
        float m[4];
        r1_forward(x, ea, src, dst, e, r1w1, r1b1, r1w2, r1b2, r1w3, r1b3, m);
        in[6] = m[0]; in[7] = m[1]; in[8] = m[2]; in[9] = m[3];
    }

    float h1[40], h2[40], z[1];
    dense<10, 40, true >(w1, b1, in, h1);
    dense<40, 40, true >(w2, b2, h1, h2);
    dense<40, 1,  false>(w3, b3, h2, z);

    out[e] = 1.f / (1.f + expf(-z[0]));
}

extern "C" void kernel_launch(void* const* d_in, const int* in_sizes, int n_in,
                              void* d_out, int out_size, void* d_ws, size_t ws_size,
                              hipStream_t stream) {
    const float* x  = (const float*)d_in[0];
    const int*   ei = (const int*)d_in[1];   // harness delivers int64 -> int32
    const float* ea = (const float*)d_in[2];

    const float* r1_w1 = (const float*)d_in[3];
    const float* r1_b1 = (const float*)d_in[4];
    const float* r1_w2 = (const float*)d_in[5];
    const float* r1_b2 = (const float*)d_in[6];
    const float* r1_w3 = (const float*)d_in[7];
    const float* r1_b3 = (const float*)d_in[8];

    const float* o_w1 = (const float*)d_in[9];
    const float* o_b1 = (const float*)d_in[10];
    const float* o_w2 = (const float*)d_in[11];
    const float* o_b2 = (const float*)d_in[12];
    const float* o_w3 = (const float*)d_in[13];
    const float* o_b3 = (const float*)d_in[14];

    const float* r2_w1 = (const float*)d_in[15];
    const float* r2_b1 = (const float*)d_in[16];
    const float* r2_w2 = (const float*)d_in[17];
    const float* r2_b2 = (const float*)d_in[18];
    const float* r2_w3 = (const float*)d_in[19];
    const float* r2_b3 = (const float*)d_in[20];

    const int n_nodes = in_sizes[0] / 3;
    const int n_edges = in_sizes[2] / 4;

    float* aggr = (float*)d_ws;                 // n_nodes * 4 floats
    float* xt   = aggr + (size_t)n_nodes * 4;   // n_nodes * 3 floats
    float* emsg = xt   + (size_t)n_nodes * 3;   // n_edges * 4 floats (optional)

    const size_t need_full = ((size_t)n_nodes * 7 + (size_t)n_edges * 4) * sizeof(float);
    const bool store_msg = ws_size >= need_full;

    const int eb = (n_edges + 255) / 256;
    const int nb = (n_nodes + 255) / 256;
    const int zb = (n_nodes * 4 + 255) / 256;

    zero_kernel<<<zb, 256, 0, stream>>>(aggr, n_nodes * 4);

    if (store_msg) {
        msg_kernel<true><<<eb, 256, 0, stream>>>(x, ei, ea,
            r1_w1, r1_b1, r1_w2, r1_b2, r1_w3, r1_b3, emsg, aggr, n_edges);
    } else {
        msg_kernel<false><<<eb, 256, 0, stream>>>(x, ei, ea,
            r1_w1, r1_b1, r1_w2, r1_b2, r1_w3, r1_b3, nullptr, aggr, n_edges);
    }

    node_kernel<<<nb, 256, 0, stream>>>(x, aggr,
        o_w1, o_b1, o_w2, o_b2, o_w3, o_b3, xt, n_nodes);

    if (store_msg) {
        out_kernel<true><<<eb, 256, 0, stream>>>(xt, ei, emsg,
            nullptr, nullptr, nullptr, nullptr, nullptr, nullptr, nullptr, nullptr,
            r2_w1, r2_b1, r2_w2, r2_b2, r2_w3, r2_b3, (float*)d_out, n_edges);
    } else {
        out_kernel<false><<<eb, 256, 0, stream>>>(xt, ei, nullptr,
            x, ea, r1_w1, r1_b1, r1_w2, r1_b2, r1_w3, r1_b3,
            r2_w1, r2_b1, r2_w2, r2_b2, r2_w3, r2_b3, (float*)d_out, n_edges);
    }
}

// Round 3
// 396.422 us; speedup vs baseline: 1.4823x; 1.4823x over previous
//
#include <hip/hip_runtime.h>
#include <math.h>

// Interaction Network:
//  K0: zero aggr (f16)
//  K1 (edges): e_msg = MLP_R1([x[dst], x[src], edge_attr]) ; aggr[dst] += e_msg (pk_f16 atomics)
//  K2 (nodes): x_tilde = MLP_O([x, aggr])
//  K3 (edges): out = sigmoid(MLP_R2([x_tilde[dst], x_tilde[src], e_msg]))
// NOTE: harness delivers integer inputs as int32 (edge_index int64 -> int32).

typedef _Float16 f16x2 __attribute__((ext_vector_type(2)));

__device__ __forceinline__ void atomic_pk_add_f16(f16x2* addr, f16x2 val) {
    // global_atomic_pk_add_f16: packed 2xf16 add, fire-and-forget (no return).
    asm volatile("global_atomic_pk_add_f16 %0, %1, off" :: "v"(addr), "v"(val) : "memory");
}

template<int IN, int OUT, bool RELU>
__device__ __forceinline__ void dense(const float* __restrict__ w,
                                      const float* __restrict__ b,
                                      const float* in, float* out) {
#pragma unroll
    for (int j = 0; j < OUT; ++j) {
        float acc = b[j];
#pragma unroll
        for (int k = 0; k < IN; ++k) acc = fmaf(w[j * IN + k], in[k], acc);
        out[j] = RELU ? fmaxf(acc, 0.f) : acc;
    }
}

__global__ __launch_bounds__(256) void zero_kernel(unsigned int* __restrict__ p, int n) {
    int i = blockIdx.x * blockDim.x + threadIdx.x;
    if (i < n) p[i] = 0u;
}

__device__ __forceinline__ void r1_forward(
    const float* __restrict__ x, const float* __restrict__ ea,
    int src, int dst, int e,
    const float* __restrict__ w1, const float* __restrict__ b1,
    const float* __restrict__ w2, const float* __restrict__ b2,
    const float* __restrict__ w3, const float* __restrict__ b3,
    float* m)
{
    float in[10];
    in[0] = x[dst * 3 + 0]; in[1] = x[dst * 3 + 1]; in[2] = x[dst * 3 + 2];
    in[3] = x[src * 3 + 0]; in[4] = x[src * 3 + 1]; in[5] = x[src * 3 + 2];
    float4 eav = *reinterpret_cast<const float4*>(ea + (size_t)e * 4);
    in[6] = eav.x; in[7] = eav.y; in[8] = eav.z; in[9] = eav.w;

    float h1[40], h2[40];
    dense<10, 40, true >(w1, b1, in, h1);
    dense<40, 40, true >(w2, b2, h1, h2);
    dense<40, 4,  false>(w3, b3, h2, m);
}

template<bool STORE_MSG>
__global__ __launch_bounds__(256) void msg_kernel(
    const float* __restrict__ x,
    const int* __restrict__ ei,
    const float* __restrict__ ea,
    const float* __restrict__ w1, const float* __restrict__ b1,
    const float* __restrict__ w2, const float* __restrict__ b2,
    const float* __restrict__ w3, const float* __restrict__ b3,
    float* __restrict__ e_msg, _Float16* __restrict__ aggr,
    int n_edges)
{
    int e = blockIdx.x * blockDim.x + threadIdx.x;
    if (e >= n_edges) return;
    int src = ei[e];
    int dst = ei[n_edges + e];

    float m[4];
    r1_forward(x, ea, src, dst, e, w1, b1, w2, b2, w3, b3, m);

    if (STORE_MSG)
        *reinterpret_cast<float4*>(e_msg + (size_t)e * 4) = make_float4(m[0], m[1], m[2], m[3]);

    f16x2 m01; m01.x = (_Float16)m[0]; m01.y = (_Float16)m[1];
    f16x2 m23; m23.x = (_Float16)m[2]; m23.y = (_Float16)m[3];
    f16x2* base = reinterpret_cast<f16x2*>(aggr + (size_t)dst * 4);
    atomic_pk_add_f16(base,     m01);
    atomic_pk_add_f16(base + 1, m23);
}

__global__ __launch_bounds__(256) void node_kernel(
    const float* __restrict__ x,
    const _Float16* __restrict__ aggr,
    const float* __restrict__ w1, const float* __restrict__ b1,
    const float* __restrict__ w2, const float* __restrict__ b2,
    const float* __restrict__ w3, const float* __restrict__ b3,
    float* __restrict__ xt,
    int n_nodes)
{
    int n = blockIdx.x * blockDim.x + threadIdx.x;
    if (n >= n_nodes) return;

    float in[7];
    in[0] = x[n * 3 + 0]; in[1] = x[n * 3 + 1]; in[2] = x[n * 3 + 2];
    const f16x2* ap = reinterpret_cast<const f16x2*>(aggr + (size_t)n * 4);
    f16x2 a01 = ap[0];
    f16x2 a23 = ap[1];
    in[3] = (float)a01.x; in[4] = (float)a01.y;
    in[5] = (float)a23.x; in[6] = (float)a23.y;

    float h1[40], h2[40], o[3];
    dense<7, 40, true >(w1, b1, in, h1);
    dense<40, 40, true>(w2, b2, h1, h2);
    dense<40, 3, false>(w3, b3, h2, o);

    xt[n * 3 + 0] = o[0]; xt[n * 3 + 1] = o[1]; xt[n * 3 + 2] = o[2];
}

template<bool LOAD_MSG>
__global__ __launch_bounds__(256) void out_kernel(
    const float* __restrict__ xt,
    const int* __restrict__ ei,
    const float* __restrict__ e_msg,
    // recompute path inputs:
    const float* __restrict__ x,
    const float* __restrict__ ea,
    const float* __restrict__ r1w1, const float* __restrict__ r1b1,
    const float* __restrict__ r1w2, const float* __restrict__ r1b2,
    const float* __restrict__ r1w3, const float* __restrict__ r1b3,
    // R2 weights:
    const float* __restrict__ w1, const float* __restrict__ b1,
    const float* __restrict__ w2, const float* __restrict__ b2,
    const float* __restrict__ w3, const float* __restrict__ b3,
    float* __restrict__ out,
    int n_edges)
{
    int e = blockIdx.x * blockDim.x + threadIdx.x;
    if (e >= n_edges) return;
    int src = ei[e];
    int dst = ei[n_edges + e];

    float in[10];
    in[0] = xt[dst * 3 + 0]; in[1] = xt[dst * 3 + 1]; in[2] = xt[dst * 3 + 2];
    in[3] = xt[src * 3 + 0]; in[4] = xt[src * 3 + 1]; in[5] = xt[src * 3 + 2];
    if (LOAD_MSG) {
        float4 mv = *reinterpret_cast<const float4*>(e_msg + (size_t)e * 4);
        in[6] = mv.x; in[7] = mv.y; in[8] = mv.z; in[9] = mv.w;
    } else {
        float m[4];
        r1_forward(x, ea, src, dst, e, r1w1, r1b1, r1w2, r1b2, r1w3, r1b3, m);
        in[6] = m[0]; in[7] = m[1]; in[8] = m[2]; in[9] = m[3];
    }

    float h1[40], h2[40], z[1];
    dense<10, 40, true >(w1, b1, in, h1);
    dense<40, 40, true >(w2, b2, h1, h2);
    dense<40, 1,  false>(w3, b3, h2, z);

    out[e] = 1.f / (1.f + expf(-z[0]));
}

extern "C" void kernel_launch(void* const* d_in, const int* in_sizes, int n_in,
                              void* d_out, int out_size, void* d_ws, size_t ws_size,
                              hipStream_t stream) {
    const float* x  = (const float*)d_in[0];
    const int*   ei = (const int*)d_in[1];   // harness delivers int64 -> int32
    const float* ea = (const float*)d_in[2];

    const float* r1_w1 = (const float*)d_in[3];
    const float* r1_b1 = (const float*)d_in[4];
    const float* r1_w2 = (const float*)d_in[5];
    const float* r1_b2 = (const float*)d_in[6];
    const float* r1_w3 = (const float*)d_in[7];
    const float* r1_b3 = (const float*)d_in[8];

    const float* o_w1 = (const float*)d_in[9];
    const float* o_b1 = (const float*)d_in[10];
    const float* o_w2 = (const float*)d_in[11];
    const float* o_b2 = (const float*)d_in[12];
    const float* o_w3 = (const float*)d_in[13];
    const float* o_b3 = (const float*)d_in[14];

    const float* r2_w1 = (const float*)d_in[15];
    const float* r2_b1 = (const float*)d_in[16];
    const float* r2_w2 = (const float*)d_in[17];
    const float* r2_b2 = (const float*)d_in[18];
    const float* r2_w3 = (const float*)d_in[19];
    const float* r2_b3 = (const float*)d_in[20];

    const int n_nodes = in_sizes[0] / 3;
    const int n_edges = in_sizes[2] / 4;

    // ws layout: aggr (f16, n_nodes*4) | xt (f32, n_nodes*3) | emsg (f32, n_edges*4)
    _Float16* aggr = (_Float16*)d_ws;
    float*    xt   = (float*)(aggr + (size_t)n_nodes * 4);
    float*    emsg = xt + (size_t)n_nodes * 3;

    const size_t need_full = (size_t)n_nodes * 4 * 2 + (size_t)n_nodes * 3 * 4
                           + (size_t)n_edges * 4 * 4;
    const bool store_msg = ws_size >= need_full;

    const int eb = (n_edges + 255) / 256;
    const int nb = (n_nodes + 255) / 256;
    const int zn = n_nodes * 2;               // dwords covering aggr
    const int zb = (zn + 255) / 256;

    zero_kernel<<<zb, 256, 0, stream>>>((unsigned int*)aggr, zn);

    if (store_msg) {
        msg_kernel<true><<<eb, 256, 0, stream>>>(x, ei, ea,
            r1_w1, r1_b1, r1_w2, r1_b2, r1_w3, r1_b3, emsg, aggr, n_edges);
    } else {
        msg_kernel<false><<<eb, 256, 0, stream>>>(x, ei, ea,
            r1_w1, r1_b1, r1_w2, r1_b2, r1_w3, r1_b3, nullptr, aggr, n_edges);
    }

    node_kernel<<<nb, 256, 0, stream>>>(x, aggr,
        o_w1, o_b1, o_w2, o_b2, o_w3, o_b3, xt, n_nodes);

    if (store_msg) {
        out_kernel<true><<<eb, 256, 0, stream>>>(xt, ei, emsg,
            nullptr, nullptr, nullptr, nullptr, nullptr, nullptr, nullptr, nullptr,
            r2_w1, r2_b1, r2_w2, r2_b2, r2_w3, r2_b3, (float*)d_out, n_edges);
    } else {
        out_kernel<false><<<eb, 256, 0, stream>>>(xt, ei, nullptr,
            x, ea, r1_w1, r1_b1, r1_w2, r1_b2, r1_w3, r1_b3,
            r2_w1, r2_b1, r2_w2, r2_b2, r2_w3, r2_b3, (float*)d_out, n_edges);
    }
}

// Round 4
// 328.392 us; speedup vs baseline: 1.7894x; 1.2072x over previous
//
#include <hip/hip_runtime.h>
#include <math.h>

// Interaction Network, MFMA edition.
//  edge MLPs (R1: 10->40->40->4, R2: 10->40->40->1) run on v_mfma_f32_32x32x16_f16,
//  32 edges per wave, edges mapped to MFMA COLUMNS so C layout
//  (col=lane&31, row=(reg&3)+8*(reg>>2)+4*(lane>>5)) puts edge e's out channels
//  in regs 0..3 of lane e (hi half lanes hold zero-padding rows 4..7).
//  Bias folded as augmented K column (feature value 1.0).
//  Aggregation unchanged: 2x global_atomic_pk_add_f16 per edge (measured floor).

typedef __fp16 hf8 __attribute__((ext_vector_type(8)));
typedef float f32x16 __attribute__((ext_vector_type(16)));

#define PITCH 56   // _Float16 slots per edge row (112 B, 16B-aligned, 7x16B)
#define NEPC  32   // edges per chunk (one MFMA tile of columns)

__device__ __forceinline__ void atomic_pk_add_f16(void* addr, unsigned val) {
    asm volatile("global_atomic_pk_add_f16 %0, %1, off" :: "v"(addr), "v"(val) : "memory");
}

__device__ __forceinline__ f32x16 mfma16(hf8 a, hf8 b, f32x16 c) {
    return __builtin_amdgcn_mfma_f32_32x32x16_f16(a, b, c, 0, 0, 0);
}

__device__ __forceinline__ unsigned pk2(float a, float b) {
    return __builtin_bit_cast(unsigned, __builtin_amdgcn_cvt_pkrtz(a, b));
}
__device__ __forceinline__ unsigned pk2_relu(float a, float b) {
    return __builtin_bit_cast(unsigned,
        __builtin_amdgcn_cvt_pkrtz(fmaxf(a, 0.f), fmaxf(b, 0.f)));
}

// A-operand fragment: W_aug[out_ch][k] with k==IN -> bias, else w[r*IN+k].
// lane: row = mt*32 + (lane&31), k = ks*16 + (lane>>5)*8 + j.
template<int IN, int OUT>
__device__ hf8 load_wfrag(const float* __restrict__ w, const float* __restrict__ b,
                          int mt, int ks, int lane) {
    const int r = mt * 32 + (lane & 31);
    const int kbase = ks * 16 + ((lane >> 5) & 1) * 8;
    hf8 f;
#pragma unroll
    for (int j = 0; j < 8; ++j) {
        const int k = kbase + j;
        float v = 0.f;
        if (r < OUT) {
            if (k < IN) v = w[r * IN + k];
            else if (k == IN) v = b[r];
        }
        f[j] = (__fp16)v;
    }
    return f;
}

#define LGKM0() do { asm volatile("s_waitcnt lgkmcnt(0)" ::: "memory"); \
                     __builtin_amdgcn_sched_barrier(0); } while (0)

// write h tile0 (rows 0..31): 4x ds_write_b64 of relu'd f16 pairs
#define WRITE_T0(ACC) do { \
    _Float16* wrb = myrow + 4 * hi; \
    _Pragma("unroll") \
    for (int q = 0; q < 4; ++q) { \
        uint2 v; v.x = pk2_relu((ACC)[4*q+0], (ACC)[4*q+1]); \
                 v.y = pk2_relu((ACC)[4*q+2], (ACC)[4*q+3]); \
        *(uint2*)(wrb + 8 * q) = v; \
    } } while (0)
// write h tile1 rows 32..39 only (rows >=40 are zero, slots 41..47 stay 0)
#define WRITE_T1(ACC) do { \
    uint2 v; v.x = pk2_relu((ACC)[0], (ACC)[1]); \
             v.y = pk2_relu((ACC)[2], (ACC)[3]); \
    *(uint2*)(myrow + 32 + 4 * hi) = v; \
    if (hi == 0) *(unsigned*)(myrow + 40) = 0x00003c00u; /* {1.0h, 0h} */ \
    } while (0)

template<bool IS_MSG>
__global__ __launch_bounds__(256) void edge_kernel(
    const float* __restrict__ xin,    // msg: x[N,3];  out: xt[N,3]
    const int*   __restrict__ ei,
    const void*  __restrict__ eattr,  // msg: ea f32[E,4];  out: emsg f16[E,4]
    const float* __restrict__ w1, const float* __restrict__ b1,
    const float* __restrict__ w2, const float* __restrict__ b2,
    const float* __restrict__ w3, const float* __restrict__ b3,
    _Float16* __restrict__ emsg_out,  // msg only
    _Float16* __restrict__ aggr,      // msg only
    float* __restrict__ out,          // out only
    int n_edges)
{
    __shared__ _Float16 sh[4][NEPC * PITCH];
    const int lane = threadIdx.x & 63;
    const int widx = threadIdx.x >> 6;
    _Float16* row0 = sh[widx];

    // ---- weight fragments (held in VGPRs for the whole kernel) ----
    hf8 wa1[2], wa2[2][3], wa3[3];
#pragma unroll
    for (int t = 0; t < 2; ++t) wa1[t] = load_wfrag<10, 40>(w1, b1, t, 0, lane);
#pragma unroll
    for (int t = 0; t < 2; ++t)
#pragma unroll
        for (int s = 0; s < 3; ++s) wa2[t][s] = load_wfrag<40, 40>(w2, b2, t, s, lane);
#pragma unroll
    for (int s = 0; s < 3; ++s)
        wa3[s] = load_wfrag<40, (IS_MSG ? 4 : 1)>(w3, b3, 0, s, lane);

    const int gwave = (int)((blockIdx.x * blockDim.x + threadIdx.x) >> 6);
    const int nwave = (int)((gridDim.x * blockDim.x) >> 6);
    const int nchunk = (n_edges + NEPC - 1) / NEPC;

    const int el = lane >> 1, half_ = lane & 1;  // staging roles
    const int ecol = lane & 31;                  // this lane's MFMA column edge
    const int hi = lane >> 5;
    _Float16* myrow = row0 + ecol * PITCH;
    const _Float16* brow = row0 + ecol * PITCH + hi * 8;  // B frag base (k = hi*8+j)

    for (int c = gwave; c < nchunk; c += nwave) {
        const int e0 = c * NEPC;
        // ---------------- stage 32 edges: feats[0..15] + zero pads ----------------
        {
            int e = e0 + el;
            int ec = e < n_edges ? e : n_edges - 1;
            _Float16* r = row0 + el * PITCH;
            if (half_ == 0) {
                int s = ei[ec], d = ei[n_edges + ec];
                *(unsigned*)(r + 0) = pk2(xin[d * 3 + 0], xin[d * 3 + 1]);
                *(unsigned*)(r + 2) = pk2(xin[d * 3 + 2], xin[s * 3 + 0]);
                *(unsigned*)(r + 4) = pk2(xin[s * 3 + 1], xin[s * 3 + 2]);
            } else {
                if (IS_MSG) {
                    const float4 ev = ((const float4*)eattr)[ec];
                    *(unsigned*)(r + 6) = pk2(ev.x, ev.y);
                    *(unsigned*)(r + 8) = pk2(ev.z, ev.w);
                } else {
                    const uint2 mv = ((const uint2*)eattr)[ec];
                    *(unsigned*)(r + 6) = mv.x;
                    *(unsigned*)(r + 8) = mv.y;
                }
                *(unsigned*)(r + 10) = 0x00003c00u;        // feat10=1.0 (bias), 11=0
                *(uint2*)(r + 12) = make_uint2(0u, 0u);    // feats 12..15
                *(uint2*)(r + 40) = make_uint2(0u, 0u);    // slots 40..43
                *(uint2*)(r + 44) = make_uint2(0u, 0u);    // slots 44..47
            }
        }
        LGKM0();

        // ---------------- layer 1: K=16 (feats 0..10 real) ----------------
        f32x16 a0 = {}, a1 = {};
        {
            hf8 bf = *(const hf8*)(brow);
            a0 = mfma16(wa1[0], bf, a0);
            a1 = mfma16(wa1[1], bf, a1);
        }
        __builtin_amdgcn_sched_barrier(0);
        WRITE_T0(a0);
        WRITE_T1(a1);
        LGKM0();

        // ---------------- layer 2: K=48 (ch 0..39 + bias@40) ----------------
        f32x16 c0 = {}, c1 = {};
        {
            hf8 b0v = *(const hf8*)(brow);
            hf8 b1v = *(const hf8*)(brow + 16);
            hf8 b2v = *(const hf8*)(brow + 32);
            c0 = mfma16(wa2[0][0], b0v, c0); c1 = mfma16(wa2[1][0], b0v, c1);
            c0 = mfma16(wa2[0][1], b1v, c0); c1 = mfma16(wa2[1][1], b1v, c1);
            c0 = mfma16(wa2[0][2], b2v, c0); c1 = mfma16(wa2[1][2], b2v, c1);
        }
        __builtin_amdgcn_sched_barrier(0);
        WRITE_T0(c0);
        WRITE_T1(c1);
        LGKM0();

        // ---------------- layer 3: K=48, M-tile 0 only ----------------
        f32x16 z0 = {};
        {
            hf8 b0v = *(const hf8*)(brow);
            hf8 b1v = *(const hf8*)(brow + 16);
            hf8 b2v = *(const hf8*)(brow + 32);
            z0 = mfma16(wa3[0], b0v, z0);
            z0 = mfma16(wa3[1], b1v, z0);
            z0 = mfma16(wa3[2], b2v, z0);
        }

        // ---------------- head ----------------
        if (hi == 0) {  // lanes 0..31: regs 0..3 = rows(=channels) 0..3 of edge ecol
            const int e = e0 + ecol;
            if (e < n_edges) {
                if (IS_MSG) {
                    unsigned m01 = pk2(z0[0], z0[1]);
                    unsigned m23 = pk2(z0[2], z0[3]);
                    *(uint2*)(emsg_out + (size_t)e * 4) = make_uint2(m01, m23);
                    const int d = ei[n_edges + e];
                    _Float16* basep = aggr + (size_t)d * 4;
                    atomic_pk_add_f16(basep, m01);
                    atomic_pk_add_f16(basep + 2, m23);
                } else {
                    out[e] = 1.f / (1.f + expf(-z0[0]));
                }
            }
        }
    }
}

__global__ __launch_bounds__(256) void zero_kernel(unsigned* __restrict__ p, int n) {
    int i = blockIdx.x * blockDim.x + threadIdx.x;
    if (i < n) p[i] = 0u;
}

template<int IN, int OUT, bool RELU>
__device__ __forceinline__ void dense(const float* __restrict__ w,
                                      const float* __restrict__ b,
                                      const float* in, float* out) {
#pragma unroll
    for (int j = 0; j < OUT; ++j) {
        float acc = b[j];
#pragma unroll
        for (int k = 0; k < IN; ++k) acc = fmaf(w[j * IN + k], in[k], acc);
        out[j] = RELU ? fmaxf(acc, 0.f) : acc;
    }
}

__global__ __launch_bounds__(256) void node_kernel(
    const float* __restrict__ x,
    const _Float16* __restrict__ aggr,
    const float* __restrict__ w1, const float* __restrict__ b1,
    const float* __restrict__ w2, const float* __restrict__ b2,
    const float* __restrict__ w3, const float* __restrict__ b3,
    float* __restrict__ xt,
    int n_nodes)
{
    int n = blockIdx.x * blockDim.x + threadIdx.x;
    if (n >= n_nodes) return;

    float in[7];
    in[0] = x[n * 3 + 0]; in[1] = x[n * 3 + 1]; in[2] = x[n * 3 + 2];
    const _Float16* ap = aggr + (size_t)n * 4;
    in[3] = (float)ap[0]; in[4] = (float)ap[1];
    in[5] = (float)ap[2]; in[6] = (float)ap[3];

    float h1[40], h2[40], o[3];
    dense<7, 40, true >(w1, b1, in, h1);
    dense<40, 40, true>(w2, b2, h1, h2);
    dense<40, 3, false>(w3, b3, h2, o);

    xt[n * 3 + 0] = o[0]; xt[n * 3 + 1] = o[1]; xt[n * 3 + 2] = o[2];
}

extern "C" void kernel_launch(void* const* d_in, const int* in_sizes, int n_in,
                              void* d_out, int out_size, void* d_ws, size_t ws_size,
                              hipStream_t stream) {
    const float* x  = (const float*)d_in[0];
    const int*   ei = (const int*)d_in[1];   // int64 delivered as int32
    const float* ea = (const float*)d_in[2];

    const float* r1_w1 = (const float*)d_in[3];
    const float* r1_b1 = (const float*)d_in[4];
    const float* r1_w2 = (const float*)d_in[5];
    const float* r1_b2 = (const float*)d_in[6];
    const float* r1_w3 = (const float*)d_in[7];
    const float* r1_b3 = (const float*)d_in[8];

    const float* o_w1 = (const float*)d_in[9];
    const float* o_b1 = (const float*)d_in[10];
    const float* o_w2 = (const float*)d_in[11];
    const float* o_b2 = (const float*)d_in[12];
    const float* o_w3 = (const float*)d_in[13];
    const float* o_b3 = (const float*)d_in[14];

    const float* r2_w1 = (const float*)d_in[15];
    const float* r2_b1 = (const float*)d_in[16];
    const float* r2_w2 = (const float*)d_in[17];
    const float* r2_b2 = (const float*)d_in[18];
    const float* r2_w3 = (const float*)d_in[19];
    const float* r2_b3 = (const float*)d_in[20];

    const int n_nodes = in_sizes[0] / 3;
    const int n_edges = in_sizes[2] / 4;

    // ws: aggr f16[N*4] | xt f32[N*3] | emsg f16[E*4]   (~18 MB, fits)
    _Float16* aggr = (_Float16*)d_ws;
    float*    xt   = (float*)(aggr + (size_t)n_nodes * 4);
    _Float16* emsg = (_Float16*)(xt + (size_t)n_nodes * 3);

    const int eb = 1024;                       // grid-stride, ~4096 waves (full residency)
    const int nb = (n_nodes + 255) / 256;
    const int zn = n_nodes * 2;                // dwords covering f16 aggr
    const int zb = (zn + 255) / 256;

    zero_kernel<<<zb, 256, 0, stream>>>((unsigned*)aggr, zn);

    edge_kernel<true><<<eb, 256, 0, stream>>>(x, ei, (const void*)ea,
        r1_w1, r1_b1, r1_w2, r1_b2, r1_w3, r1_b3,
        emsg, aggr, nullptr, n_edges);

    node_kernel<<<nb, 256, 0, stream>>>(x, aggr,
        o_w1, o_b1, o_w2, o_b2, o_w3, o_b3, xt, n_nodes);

    edge_kernel<false><<<eb, 256, 0, stream>>>(xt, ei, (const void*)emsg,
        r2_w1, r2_b1, r2_w2, r2_b2, r2_w3, r2_b3,
        nullptr, nullptr, (float*)d_out, n_edges);
}

// Round 5
// 317.559 us; speedup vs baseline: 1.8504x; 1.0341x over previous
//
#include <hip/hip_runtime.h>
#include <math.h>

// Interaction Network, MFMA + LDS-binned aggregation (no global atomics).
//  K1 msg  (edges): emsg = MLP_R1([x[dst],x[src],ea]) via mfma_32x32x16_f16
//  K2 bin  (B x W blocks): LDS f32 bins over 4096-node ranges; scan edge chunk,
//          ds-atomic-add in-bin messages; flush partials to scratch (plain stores)
//  K3 red  (nodes): aggr[n] = sum_w partial[b][w][n]   (f32, coalesced)
//  K4 node (nodes): xt = MLP_O([x, aggr])              (scalar fp32)
//  K5 out  (edges): out = sigmoid(MLP_R2([xt[dst],xt[src],emsg])) via MFMA

typedef __fp16 hf8 __attribute__((ext_vector_type(8)));
typedef _Float16 f16x2 __attribute__((ext_vector_type(2)));
typedef float f32x16 __attribute__((ext_vector_type(16)));

#define PITCH 56   // _Float16 slots per edge row (112 B)
#define NEPC  32   // edges per wave-chunk (one MFMA column tile)
#define BS    4096 // nodes per aggregation bin
#define NW    8    // edge chunks (replicas per bin)

__device__ __forceinline__ f32x16 mfma16(hf8 a, hf8 b, f32x16 c) {
    return __builtin_amdgcn_mfma_f32_32x32x16_f16(a, b, c, 0, 0, 0);
}
__device__ __forceinline__ unsigned pk2(float a, float b) {
    return __builtin_bit_cast(unsigned, __builtin_amdgcn_cvt_pkrtz(a, b));
}
__device__ __forceinline__ unsigned pk2_relu(float a, float b) {
    return __builtin_bit_cast(unsigned,
        __builtin_amdgcn_cvt_pkrtz(fmaxf(a, 0.f), fmaxf(b, 0.f)));
}

template<int IN, int OUT>
__device__ hf8 load_wfrag(const float* __restrict__ w, const float* __restrict__ b,
                          int mt, int ks, int lane) {
    const int r = mt * 32 + (lane & 31);
    const int kbase = ks * 16 + ((lane >> 5) & 1) * 8;
    hf8 f;
#pragma unroll
    for (int j = 0; j < 8; ++j) {
        const int k = kbase + j;
        float v = 0.f;
        if (r < OUT) {
            if (k < IN) v = w[r * IN + k];
            else if (k == IN) v = b[r];
        }
        f[j] = (__fp16)v;
    }
    return f;
}

#define LGKM0() do { asm volatile("s_waitcnt lgkmcnt(0)" ::: "memory"); \
                     __builtin_amdgcn_sched_barrier(0); } while (0)

#define WRITE_T0(ACC) do { \
    _Float16* wrb = myrow + 4 * hi; \
    _Pragma("unroll") \
    for (int q = 0; q < 4; ++q) { \
        uint2 v; v.x = pk2_relu((ACC)[4*q+0], (ACC)[4*q+1]); \
                 v.y = pk2_relu((ACC)[4*q+2], (ACC)[4*q+3]); \
        *(uint2*)(wrb + 8 * q) = v; \
    } } while (0)
#define WRITE_T1(ACC) do { \
    uint2 v; v.x = pk2_relu((ACC)[0], (ACC)[1]); \
             v.y = pk2_relu((ACC)[2], (ACC)[3]); \
    *(uint2*)(myrow + 32 + 4 * hi) = v; \
    if (hi == 0) *(unsigned*)(myrow + 40) = 0x00003c00u; /* {1.0h, 0h} */ \
    } while (0)

template<bool IS_MSG>
__global__ __launch_bounds__(256) void edge_kernel(
    const float* __restrict__ xin,    // msg: x[N,3];  out: xt[N,3]
    const int*   __restrict__ ei,
    const void*  __restrict__ eattr,  // msg: ea f32[E,4];  out: emsg f16[E,4]
    const float* __restrict__ w1, const float* __restrict__ b1,
    const float* __restrict__ w2, const float* __restrict__ b2,
    const float* __restrict__ w3, const float* __restrict__ b3,
    _Float16* __restrict__ emsg_out,  // msg only
    float* __restrict__ out,          // out only
    int n_edges)
{
    __shared__ _Float16 sh[4][NEPC * PITCH];
    const int lane = threadIdx.x & 63;
    const int widx = threadIdx.x >> 6;
    _Float16* row0 = sh[widx];

    hf8 wa1[2], wa2[2][3], wa3[3];
#pragma unroll
    for (int t = 0; t < 2; ++t) wa1[t] = load_wfrag<10, 40>(w1, b1, t, 0, lane);
#pragma unroll
    for (int t = 0; t < 2; ++t)
#pragma unroll
        for (int s = 0; s < 3; ++s) wa2[t][s] = load_wfrag<40, 40>(w2, b2, t, s, lane);
#pragma unroll
    for (int s = 0; s < 3; ++s)
        wa3[s] = load_wfrag<40, (IS_MSG ? 4 : 1)>(w3, b3, 0, s, lane);

    const int gwave = (int)((blockIdx.x * blockDim.x + threadIdx.x) >> 6);
    const int nwave = (int)((gridDim.x * blockDim.x) >> 6);
    const int nchunk = (n_edges + NEPC - 1) / NEPC;

    const int el = lane >> 1, half_ = lane & 1;
    const int ecol = lane & 31;
    const int hi = lane >> 5;
    _Float16* myrow = row0 + ecol * PITCH;
    const _Float16* brow = row0 + ecol * PITCH + hi * 8;

    for (int c = gwave; c < nchunk; c += nwave) {
        const int e0 = c * NEPC;
        // stage 32 edges
        {
            int e = e0 + el;
            int ec = e < n_edges ? e : n_edges - 1;
            _Float16* r = row0 + el * PITCH;
            if (half_ == 0) {
                int s = ei[ec], d = ei[n_edges + ec];
                *(unsigned*)(r + 0) = pk2(xin[d * 3 + 0], xin[d * 3 + 1]);
                *(unsigned*)(r + 2) = pk2(xin[d * 3 + 2], xin[s * 3 + 0]);
                *(unsigned*)(r + 4) = pk2(xin[s * 3 + 1], xin[s * 3 + 2]);
            } else {
                if (IS_MSG) {
                    const float4 ev = ((const float4*)eattr)[ec];
                    *(unsigned*)(r + 6) = pk2(ev.x, ev.y);
                    *(unsigned*)(r + 8) = pk2(ev.z, ev.w);
                } else {
                    const uint2 mv = ((const uint2*)eattr)[ec];
                    *(unsigned*)(r + 6) = mv.x;
                    *(unsigned*)(r + 8) = mv.y;
                }
                *(unsigned*)(r + 10) = 0x00003c00u;
                *(uint2*)(r + 12) = make_uint2(0u, 0u);
                *(uint2*)(r + 40) = make_uint2(0u, 0u);
                *(uint2*)(r + 44) = make_uint2(0u, 0u);
            }
        }
        LGKM0();

        // layer 1
        f32x16 a0 = {}, a1 = {};
        {
            hf8 bf = *(const hf8*)(brow);
            a0 = mfma16(wa1[0], bf, a0);
            a1 = mfma16(wa1[1], bf, a1);
        }
        __builtin_amdgcn_sched_barrier(0);
        WRITE_T0(a0);
        WRITE_T1(a1);
        LGKM0();

        // layer 2
        f32x16 c0 = {}, c1 = {};
        {
            hf8 b0v = *(const hf8*)(brow);
            hf8 b1v = *(const hf8*)(brow + 16);
            hf8 b2v = *(const hf8*)(brow + 32);
            c0 = mfma16(wa2[0][0], b0v, c0); c1 = mfma16(wa2[1][0], b0v, c1);
            c0 = mfma16(wa2[0][1], b1v, c0); c1 = mfma16(wa2[1][1], b1v, c1);
            c0 = mfma16(wa2[0][2], b2v, c0); c1 = mfma16(wa2[1][2], b2v, c1);
        }
        __builtin_amdgcn_sched_barrier(0);
        WRITE_T0(c0);
        WRITE_T1(c1);
        LGKM0();

        // layer 3
        f32x16 z0 = {};
        {
            hf8 b0v = *(const hf8*)(brow);
            hf8 b1v = *(const hf8*)(brow + 16);
            hf8 b2v = *(const hf8*)(brow + 32);
            z0 = mfma16(wa3[0], b0v, z0);
            z0 = mfma16(wa3[1], b1v, z0);
            z0 = mfma16(wa3[2], b2v, z0);
        }

        // head
        if (hi == 0) {
            const int e = e0 + ecol;
            if (e < n_edges) {
                if (IS_MSG) {
                    unsigned m01 = pk2(z0[0], z0[1]);
                    unsigned m23 = pk2(z0[2], z0[3]);
                    *(uint2*)(emsg_out + (size_t)e * 4) = make_uint2(m01, m23);
                } else {
                    out[e] = 1.f / (1.f + expf(-z0[0]));
                }
            }
        }
    }
}

// ---- aggregation phase 1: per-(bin, edge-chunk) LDS accumulation ----
__global__ __launch_bounds__(1024) void bin_kernel(
    const int* __restrict__ ei,
    const uint2* __restrict__ emsg,   // f16[E][4] viewed as uint2
    float* __restrict__ scratch,      // [B*NW][BS*4]
    int n_edges)
{
    __shared__ float bin[BS * 4];     // 64 KB
    const int w = blockIdx.x / ((gridDim.x + NW - 1) / NW);  // not used; see below
    (void)w;
    // decode: blocks laid out as w-major groups of B bins
    // gridDim.x == B*NW;  B = gridDim.x / NW
    const int B = gridDim.x / NW;
    const int wchunk = blockIdx.x / B;
    const int b = blockIdx.x % B;
    const int bbase = b * BS;
    const int tid = threadIdx.x;

#pragma unroll
    for (int i = 0; i < (BS * 4) / 1024; ++i)
        bin[tid + i * 1024] = 0.f;
    __syncthreads();

    const long long e0 = (long long)n_edges * wchunk / NW;
    const long long e1 = (long long)n_edges * (wchunk + 1) / NW;
    for (long long e = e0 + tid; e < e1; e += 1024) {
        const int d = ei[n_edges + e];
        const unsigned nl = (unsigned)(d - bbase);
        if (nl < (unsigned)BS) {
            const uint2 mv = emsg[e];
            f16x2 lo = __builtin_bit_cast(f16x2, mv.x);
            f16x2 hi = __builtin_bit_cast(f16x2, mv.y);
            float* p = bin + nl * 4;
            atomicAdd(p + 0, (float)lo.x);
            atomicAdd(p + 1, (float)lo.y);
            atomicAdd(p + 2, (float)hi.x);
            atomicAdd(p + 3, (float)hi.y);
        }
    }
    __syncthreads();

    float4* dst = (float4*)(scratch + ((size_t)(b * NW + wchunk)) * BS * 4);
    const float4* srcb = (const float4*)bin;
#pragma unroll
    for (int i = 0; i < (BS * 4) / 4 / 1024; ++i)
        dst[tid + i * 1024] = srcb[tid + i * 1024];
}

// ---- aggregation phase 2: sum chunk partials -> aggr f32[N][4] ----
__global__ __launch_bounds__(256) void reduce_kernel(
    const float* __restrict__ scratch,
    float* __restrict__ aggr,
    int n_nodes)
{
    int n = blockIdx.x * blockDim.x + threadIdx.x;
    if (n >= n_nodes) return;
    const int b = n / BS, nl = n % BS;
    float4 acc = make_float4(0.f, 0.f, 0.f, 0.f);
#pragma unroll
    for (int w = 0; w < NW; ++w) {
        const float4 v = *(const float4*)(scratch + ((size_t)(b * NW + w) * BS + nl) * 4);
        acc.x += v.x; acc.y += v.y; acc.z += v.z; acc.w += v.w;
    }
    *(float4*)(aggr + (size_t)n * 4) = acc;
}

template<int IN, int OUT, bool RELU>
__device__ __forceinline__ void dense(const float* __restrict__ w,
                                      const float* __restrict__ b,
                                      const float* in, float* out) {
#pragma unroll
    for (int j = 0; j < OUT; ++j) {
        float acc = b[j];
#pragma unroll
        for (int k = 0; k < IN; ++k) acc = fmaf(w[j * IN + k], in[k], acc);
        out[j] = RELU ? fmaxf(acc, 0.f) : acc;
    }
}

__global__ __launch_bounds__(256) void node_kernel(
    const float* __restrict__ x,
    const float* __restrict__ aggr,
    const float* __restrict__ w1, const float* __restrict__ b1,
    const float* __restrict__ w2, const float* __restrict__ b2,
    const float* __restrict__ w3, const float* __restrict__ b3,
    float* __restrict__ xt,
    int n_nodes)
{
    int n = blockIdx.x * blockDim.x + threadIdx.x;
    if (n >= n_nodes) return;

    float in[7];
    in[0] = x[n * 3 + 0]; in[1] = x[n * 3 + 1]; in[2] = x[n * 3 + 2];
    const float4 ag = *(const float4*)(aggr + (size_t)n * 4);
    in[3] = ag.x; in[4] = ag.y; in[5] = ag.z; in[6] = ag.w;

    float h1[40], h2[40], o[3];
    dense<7, 40, true >(w1, b1, in, h1);
    dense<40, 40, true>(w2, b2, h1, h2);
    dense<40, 3, false>(w3, b3, h2, o);

    xt[n * 3 + 0] = o[0]; xt[n * 3 + 1] = o[1]; xt[n * 3 + 2] = o[2];
}

extern "C" void kernel_launch(void* const* d_in, const int* in_sizes, int n_in,
                              void* d_out, int out_size, void* d_ws, size_t ws_size,
                              hipStream_t stream) {
    const float* x  = (const float*)d_in[0];
    const int*   ei = (const int*)d_in[1];   // int64 delivered as int32
    const float* ea = (const float*)d_in[2];

    const float* r1_w1 = (const float*)d_in[3];
    const float* r1_b1 = (const float*)d_in[4];
    const float* r1_w2 = (const float*)d_in[5];
    const float* r1_b2 = (const float*)d_in[6];
    const float* r1_w3 = (const float*)d_in[7];
    const float* r1_b3 = (const float*)d_in[8];

    const float* o_w1 = (const float*)d_in[9];
    const float* o_b1 = (const float*)d_in[10];
    const float* o_w2 = (const float*)d_in[11];
    const float* o_b2 = (const float*)d_in[12];
    const float* o_w3 = (const float*)d_in[13];
    const float* o_b3 = (const float*)d_in[14];

    const float* r2_w1 = (const float*)d_in[15];
    const float* r2_b1 = (const float*)d_in[16];
    const float* r2_w2 = (const float*)d_in[17];
    const float* r2_b2 = (const float*)d_in[18];
    const float* r2_w3 = (const float*)d_in[19];
    const float* r2_b3 = (const float*)d_in[20];

    const int n_nodes = in_sizes[0] / 3;
    const int n_edges = in_sizes[2] / 4;
    const int B = (n_nodes + BS - 1) / BS;

    // ws: aggr f32[N*4] | xt f32[N*3] | emsg f16[E*4] | scratch f32[B*NW*BS*4]
    float*    aggr    = (float*)d_ws;
    float*    xt      = aggr + (size_t)n_nodes * 4;
    _Float16* emsg    = (_Float16*)(xt + (size_t)n_nodes * 3);
    float*    scratch = (float*)(emsg + (size_t)n_edges * 4);

    const int eb = 1024;
    const int nb = (n_nodes + 255) / 256;

    edge_kernel<true><<<eb, 256, 0, stream>>>(x, ei, (const void*)ea,
        r1_w1, r1_b1, r1_w2, r1_b2, r1_w3, r1_b3,
        emsg, nullptr, n_edges);

    bin_kernel<<<B * NW, 1024, 0, stream>>>(ei, (const uint2*)emsg, scratch, n_edges);

    reduce_kernel<<<nb, 256, 0, stream>>>(scratch, aggr, n_nodes);

    node_kernel<<<nb, 256, 0, stream>>>(x, aggr,
        o_w1, o_b1, o_w2, o_b2, o_w3, o_b3, xt, n_nodes);

    edge_kernel<false><<<eb, 256, 0, stream>>>(xt, ei, (const void*)emsg,
        r2_w1, r2_b1, r2_w2, r2_b2, r2_w3, r2_b3,
        nullptr, (float*)d_out, n_edges);
}

// Round 6
// 240.528 us; speedup vs baseline: 2.4430x; 1.3203x over previous
//
#include <hip/hip_runtime.h>
#include <math.h>

// Interaction Network, MFMA + LDS-binned aggregation (no global atomics).
//  K1 msg  (edges): emsg = MLP_R1([x[dst],x[src],ea]) via mfma_32x32x16_f16
//  K2 bin  (B x NW blocks): LDS f32 bins over 4096-node ranges; scan edge chunk
//          with x4-unrolled dwordx4 dst loads; ds-atomic-add in-bin messages;
//          flush partials to scratch (plain coalesced stores)
//  K3 red  (nodes): aggr[n] = sum_w partial[b][w][n]   (f32, coalesced)
//  K4 node (nodes): xt = MLP_O([x, aggr])              (scalar fp32)
//  K5 out  (edges): out = sigmoid(MLP_R2([xt[dst],xt[src],emsg])) via MFMA

typedef __fp16 hf8 __attribute__((ext_vector_type(8)));
typedef _Float16 f16x2 __attribute__((ext_vector_type(2)));
typedef float f32x16 __attribute__((ext_vector_type(16)));

#define PITCH 56   // _Float16 slots per edge row (112 B)
#define NEPC  32   // edges per wave-chunk (one MFMA column tile)
#define BS    4096 // nodes per aggregation bin

__device__ __forceinline__ f32x16 mfma16(hf8 a, hf8 b, f32x16 c) {
    return __builtin_amdgcn_mfma_f32_32x32x16_f16(a, b, c, 0, 0, 0);
}
__device__ __forceinline__ unsigned pk2(float a, float b) {
    return __builtin_bit_cast(unsigned, __builtin_amdgcn_cvt_pkrtz(a, b));
}
__device__ __forceinline__ unsigned pk2_relu(float a, float b) {
    return __builtin_bit_cast(unsigned,
        __builtin_amdgcn_cvt_pkrtz(fmaxf(a, 0.f), fmaxf(b, 0.f)));
}

template<int IN, int OUT>
__device__ hf8 load_wfrag(const float* __restrict__ w, const float* __restrict__ b,
                          int mt, int ks, int lane) {
    const int r = mt * 32 + (lane & 31);
    const int kbase = ks * 16 + ((lane >> 5) & 1) * 8;
    hf8 f;
#pragma unroll
    for (int j = 0; j < 8; ++j) {
        const int k = kbase + j;
        float v = 0.f;
        if (r < OUT) {
            if (k < IN) v = w[r * IN + k];
            else if (k == IN) v = b[r];
        }
        f[j] = (__fp16)v;
    }
    return f;
}

#define LGKM0() do { asm volatile("s_waitcnt lgkmcnt(0)" ::: "memory"); \
                     __builtin_amdgcn_sched_barrier(0); } while (0)

#define WRITE_T0(ACC) do { \
    _Float16* wrb = myrow + 4 * hi; \
    _Pragma("unroll") \
    for (int q = 0; q < 4; ++q) { \
        uint2 v; v.x = pk2_relu((ACC)[4*q+0], (ACC)[4*q+1]); \
                 v.y = pk2_relu((ACC)[4*q+2], (ACC)[4*q+3]); \
        *(uint2*)(wrb + 8 * q) = v; \
    } } while (0)
#define WRITE_T1(ACC) do { \
    uint2 v; v.x = pk2_relu((ACC)[0], (ACC)[1]); \
             v.y = pk2_relu((ACC)[2], (ACC)[3]); \
    *(uint2*)(myrow + 32 + 4 * hi) = v; \
    if (hi == 0) *(unsigned*)(myrow + 40) = 0x00003c00u; /* {1.0h, 0h} */ \
    } while (0)

template<bool IS_MSG>
__global__ __launch_bounds__(256) void edge_kernel(
    const float* __restrict__ xin,    // msg: x[N,3];  out: xt[N,3]
    const int*   __restrict__ ei,
    const void*  __restrict__ eattr,  // msg: ea f32[E,4];  out: emsg f16[E,4]
    const float* __restrict__ w1, const float* __restrict__ b1,
    const float* __restrict__ w2, const float* __restrict__ b2,
    const float* __restrict__ w3, const float* __restrict__ b3,
    _Float16* __restrict__ emsg_out,  // msg only
    float* __restrict__ out,          // out only
    int n_edges)
{
    __shared__ _Float16 sh[4][NEPC * PITCH];
    const int lane = threadIdx.x & 63;
    const int widx = threadIdx.x >> 6;
    _Float16* row0 = sh[widx];

    hf8 wa1[2], wa2[2][3], wa3[3];
#pragma unroll
    for (int t = 0; t < 2; ++t) wa1[t] = load_wfrag<10, 40>(w1, b1, t, 0, lane);
#pragma unroll
    for (int t = 0; t < 2; ++t)
#pragma unroll
        for (int s = 0; s < 3; ++s) wa2[t][s] = load_wfrag<40, 40>(w2, b2, t, s, lane);
#pragma unroll
    for (int s = 0; s < 3; ++s)
        wa3[s] = load_wfrag<40, (IS_MSG ? 4 : 1)>(w3, b3, 0, s, lane);

    const int gwave = (int)((blockIdx.x * blockDim.x + threadIdx.x) >> 6);
    const int nwave = (int)((gridDim.x * blockDim.x) >> 6);
    const int nchunk = (n_edges + NEPC - 1) / NEPC;

    const int el = lane >> 1, half_ = lane & 1;
    const int ecol = lane & 31;
    const int hi = lane >> 5;
    _Float16* myrow = row0 + ecol * PITCH;
    const _Float16* brow = row0 + ecol * PITCH + hi * 8;

    for (int c = gwave; c < nchunk; c += nwave) {
        const int e0 = c * NEPC;
        // stage 32 edges
        {
            int e = e0 + el;
            int ec = e < n_edges ? e : n_edges - 1;
            _Float16* r = row0 + el * PITCH;
            if (half_ == 0) {
                int s = ei[ec], d = ei[n_edges + ec];
                *(unsigned*)(r + 0) = pk2(xin[d * 3 + 0], xin[d * 3 + 1]);
                *(unsigned*)(r + 2) = pk2(xin[d * 3 + 2], xin[s * 3 + 0]);
                *(unsigned*)(r + 4) = pk2(xin[s * 3 + 1], xin[s * 3 + 2]);
            } else {
                if (IS_MSG) {
                    const float4 ev = ((const float4*)eattr)[ec];
                    *(unsigned*)(r + 6) = pk2(ev.x, ev.y);
                    *(unsigned*)(r + 8) = pk2(ev.z, ev.w);
                } else {
                    const uint2 mv = ((const uint2*)eattr)[ec];
                    *(unsigned*)(r + 6) = mv.x;
                    *(unsigned*)(r + 8) = mv.y;
                }
                *(unsigned*)(r + 10) = 0x00003c00u;
                *(uint2*)(r + 12) = make_uint2(0u, 0u);
                *(uint2*)(r + 40) = make_uint2(0u, 0u);
                *(uint2*)(r + 44) = make_uint2(0u, 0u);
            }
        }
        LGKM0();

        // layer 1
        f32x16 a0 = {}, a1 = {};
        {
            hf8 bf = *(const hf8*)(brow);
            a0 = mfma16(wa1[0], bf, a0);
            a1 = mfma16(wa1[1], bf, a1);
        }
        __builtin_amdgcn_sched_barrier(0);
        WRITE_T0(a0);
        WRITE_T1(a1);
        LGKM0();

        // layer 2
        f32x16 c0 = {}, c1 = {};
        {
            hf8 b0v = *(const hf8*)(brow);
            hf8 b1v = *(const hf8*)(brow + 16);
            hf8 b2v = *(const hf8*)(brow + 32);
            c0 = mfma16(wa2[0][0], b0v, c0); c1 = mfma16(wa2[1][0], b0v, c1);
            c0 = mfma16(wa2[0][1], b1v, c0); c1 = mfma16(wa2[1][1], b1v, c1);
            c0 = mfma16(wa2[0][2], b2v, c0); c1 = mfma16(wa2[1][2], b2v, c1);
        }
        __builtin_amdgcn_sched_barrier(0);
        WRITE_T0(c0);
        WRITE_T1(c1);
        LGKM0();

        // layer 3
        f32x16 z0 = {};
        {
            hf8 b0v = *(const hf8*)(brow);
            hf8 b1v = *(const hf8*)(brow + 16);
            hf8 b2v = *(const hf8*)(brow + 32);
            z0 = mfma16(wa3[0], b0v, z0);
            z0 = mfma16(wa3[1], b1v, z0);
            z0 = mfma16(wa3[2], b2v, z0);
        }

        // head
        if (hi == 0) {
            const int e = e0 + ecol;
            if (e < n_edges) {
                if (IS_MSG) {
                    unsigned m01 = pk2(z0[0], z0[1]);
                    unsigned m23 = pk2(z0[2], z0[3]);
                    *(uint2*)(emsg_out + (size_t)e * 4) = make_uint2(m01, m23);
                } else {
                    out[e] = 1.f / (1.f + expf(-z0[0]));
                }
            }
        }
    }
}

// ---- aggregation phase 1: per-(bin, edge-chunk) LDS accumulation ----
__device__ __forceinline__ void bin_accum(float* __restrict__ bin, int bbase, int d,
                                          const uint2* __restrict__ emsg, long long e) {
    const unsigned nl = (unsigned)(d - bbase);
    if (nl < (unsigned)BS) {
        const uint2 mv = emsg[e];
        f16x2 lo = __builtin_bit_cast(f16x2, mv.x);
        f16x2 hi = __builtin_bit_cast(f16x2, mv.y);
        float* p = bin + nl * 4;
        atomicAdd(p + 0, (float)lo.x);
        atomicAdd(p + 1, (float)lo.y);
        atomicAdd(p + 2, (float)hi.x);
        atomicAdd(p + 3, (float)hi.y);
    }
}

__global__ __launch_bounds__(1024) void bin_kernel(
    const int* __restrict__ ei,
    const uint2* __restrict__ emsg,   // f16[E][4] viewed as uint2
    float* __restrict__ scratch,      // [B*NW][BS*4]
    int n_edges, int nw)
{
    __shared__ float bin[BS * 4];     // 64 KB
    const int B = gridDim.x / nw;
    const int wchunk = blockIdx.x / B;
    const int b = blockIdx.x % B;
    const int bbase = b * BS;
    const int tid = threadIdx.x;

#pragma unroll
    for (int i = 0; i < (BS * 4) / 1024; ++i)
        bin[tid + i * 1024] = 0.f;
    __syncthreads();

    // 16B-aligned chunk boundaries so dwordx4 dst loads are legal
    long long e0 = ((long long)n_edges * wchunk / nw) & ~3LL;
    long long e1 = (wchunk == nw - 1) ? (long long)n_edges
                                      : (((long long)n_edges * (wchunk + 1) / nw) & ~3LL);
    const long long nfull = (e1 - e0) >> 2;            // count of int4 groups
    const int* dstp = ei + n_edges;

    for (long long g = tid; g < nfull; g += 1024) {
        const long long e = e0 + g * 4;
        const int4 d4 = *(const int4*)(dstp + e);
        bin_accum(bin, bbase, d4.x, emsg, e + 0);
        bin_accum(bin, bbase, d4.y, emsg, e + 1);
        bin_accum(bin, bbase, d4.z, emsg, e + 2);
        bin_accum(bin, bbase, d4.w, emsg, e + 3);
    }
    // tail (0..3 edges)
    for (long long e = e0 + nfull * 4 + tid; e < e1; e += 1024)
        bin_accum(bin, bbase, dstp[e], emsg, e);

    __syncthreads();

    float4* dst = (float4*)(scratch + ((size_t)(b * nw + wchunk)) * BS * 4);
    const float4* srcb = (const float4*)bin;
#pragma unroll
    for (int i = 0; i < (BS * 4) / 4 / 1024; ++i)
        dst[tid + i * 1024] = srcb[tid + i * 1024];
}

// ---- aggregation phase 2: sum chunk partials -> aggr f32[N][4] ----
__global__ __launch_bounds__(256) void reduce_kernel(
    const float* __restrict__ scratch,
    float* __restrict__ aggr,
    int n_nodes, int nw)
{
    int n = blockIdx.x * blockDim.x + threadIdx.x;
    if (n >= n_nodes) return;
    const int b = n / BS, nl = n % BS;
    float4 acc = make_float4(0.f, 0.f, 0.f, 0.f);
    for (int w = 0; w < nw; ++w) {
        const float4 v = *(const float4*)(scratch + ((size_t)(b * nw + w) * BS + nl) * 4);
        acc.x += v.x; acc.y += v.y; acc.z += v.z; acc.w += v.w;
    }
    *(float4*)(aggr + (size_t)n * 4) = acc;
}

template<int IN, int OUT, bool RELU>
__device__ __forceinline__ void dense(const float* __restrict__ w,
                                      const float* __restrict__ b,
                                      const float* in, float* out) {
#pragma unroll
    for (int j = 0; j < OUT; ++j) {
        float acc = b[j];
#pragma unroll
        for (int k = 0; k < IN; ++k) acc = fmaf(w[j * IN + k], in[k], acc);
        out[j] = RELU ? fmaxf(acc, 0.f) : acc;
    }
}

__global__ __launch_bounds__(256) void node_kernel(
    const float* __restrict__ x,
    const float* __restrict__ aggr,
    const float* __restrict__ w1, const float* __restrict__ b1,
    const float* __restrict__ w2, const float* __restrict__ b2,
    const float* __restrict__ w3, const float* __restrict__ b3,
    float* __restrict__ xt,
    int n_nodes)
{
    int n = blockIdx.x * blockDim.x + threadIdx.x;
    if (n >= n_nodes) return;

    float in[7];
    in[0] = x[n * 3 + 0]; in[1] = x[n * 3 + 1]; in[2] = x[n * 3 + 2];
    const float4 ag = *(const float4*)(aggr + (size_t)n * 4);
    in[3] = ag.x; in[4] = ag.y; in[5] = ag.z; in[6] = ag.w;

    float h1[40], h2[40], o[3];
    dense<7, 40, true >(w1, b1, in, h1);
    dense<40, 40, true>(w2, b2, h1, h2);
    dense<40, 3, false>(w3, b3, h2, o);

    xt[n * 3 + 0] = o[0]; xt[n * 3 + 1] = o[1]; xt[n * 3 + 2] = o[2];
}

extern "C" void kernel_launch(void* const* d_in, const int* in_sizes, int n_in,
                              void* d_out, int out_size, void* d_ws, size_t ws_size,
                              hipStream_t stream) {
    const float* x  = (const float*)d_in[0];
    const int*   ei = (const int*)d_in[1];   // int64 delivered as int32
    const float* ea = (const float*)d_in[2];

    const float* r1_w1 = (const float*)d_in[3];
    const float* r1_b1 = (const float*)d_in[4];
    const float* r1_w2 = (const float*)d_in[5];
    const float* r1_b2 = (const float*)d_in[6];
    const float* r1_w3 = (const float*)d_in[7];
    const float* r1_b3 = (const float*)d_in[8];

    const float* o_w1 = (const float*)d_in[9];
    const float* o_b1 = (const float*)d_in[10];
    const float* o_w2 = (const float*)d_in[11];
    const float* o_b2 = (const float*)d_in[12];
    const float* o_w3 = (const float*)d_in[13];
    const float* o_b3 = (const float*)d_in[14];

    const float* r2_w1 = (const float*)d_in[15];
    const float* r2_b1 = (const float*)d_in[16];
    const float* r2_w2 = (const float*)d_in[17];
    const float* r2_b2 = (const float*)d_in[18];
    const float* r2_w3 = (const float*)d_in[19];
    const float* r2_b3 = (const float*)d_in[20];

    const int n_nodes = in_sizes[0] / 3;
    const int n_edges = in_sizes[2] / 4;
    const int B = (n_nodes + BS - 1) / BS;

    // ws: aggr f32[N*4] | xt f32[N*3] | emsg f16[E*4] | scratch f32[B*NW*BS*4]
    float*    aggr    = (float*)d_ws;
    float*    xt      = aggr + (size_t)n_nodes * 4;
    _Float16* emsg    = (_Float16*)(xt + (size_t)n_nodes * 3);
    float*    scratch = (float*)(emsg + (size_t)n_edges * 4);

    const size_t fixed_bytes = (size_t)n_nodes * 4 * 4 + (size_t)n_nodes * 3 * 4
                             + (size_t)n_edges * 4 * 2;
    int nw = 16;
    if (ws_size < fixed_bytes + (size_t)B * nw * BS * 4 * sizeof(float)) nw = 8;

    const int eb = 2048;
    const int nb = (n_nodes + 255) / 256;

    edge_kernel<true><<<eb, 256, 0, stream>>>(x, ei, (const void*)ea,
        r1_w1, r1_b1, r1_w2, r1_b2, r1_w3, r1_b3,
        emsg, nullptr, n_edges);

    bin_kernel<<<B * nw, 1024, 0, stream>>>(ei, (const uint2*)emsg, scratch,
                                            n_edges, nw);

    reduce_kernel<<<nb, 256, 0, stream>>>(scratch, aggr, n_nodes, nw);

    node_kernel<<<nb, 256, 0, stream>>>(x, aggr,
        o_w1, o_b1, o_w2, o_b2, o_w3, o_b3, xt, n_nodes);

    edge_kernel<false><<<eb, 256, 0, stream>>>(xt, ei, (const void*)emsg,
        r2_w1, r2_b1, r2_w2, r2_b2, r2_w3, r2_b3,
        nullptr, (float*)d_out, n_edges);
}

// Round 7
// 235.427 us; speedup vs baseline: 2.4960x; 1.0217x over previous
//
#include <hip/hip_runtime.h>
#include <math.h>

// Interaction Network, MFMA + software-pipelined staging + LDS-binned aggregation.
//  K0 nodef (nodes): pack x -> f16x4 {x0,x1,x2,0}
//  K1 msg   (edges): emsg = MLP_R1([x[dst],x[src],ea]) via mfma_32x32x16_f16,
//           2-deep modulo-scheduled staging (idx prefetch -> feat gather -> LDS)
//  K2 bin   (B x NW blocks): LDS f32 bins; scan edge chunk; flush partials
//  K3 red   (nodes): aggr[n] = sum_w partial[b][w][n]
//  K4 node  (nodes): xt = MLP_O([x, aggr]) -> packed f16x4 (reuses nodef buffer)
//  K5 out   (edges): out = sigmoid(MLP_R2([xt[dst],xt[src],emsg])) via MFMA
// Layer-1 K layout (padded, weights remapped to match):
//  k: 0-2 xd | 3 pad | 4-6 xs | 7 pad | 8-11 ea/msg | 12 bias(1.0) | 13-15 pad

typedef __fp16 hf8 __attribute__((ext_vector_type(8)));
typedef _Float16 f16x2 __attribute__((ext_vector_type(2)));
typedef float f32x16 __attribute__((ext_vector_type(16)));

#define PITCH 56   // _Float16 slots per edge row (112 B)
#define NEPC  32   // edges per wave-chunk (one MFMA column tile)
#define BS    4096 // nodes per aggregation bin

__device__ __forceinline__ f32x16 mfma16(hf8 a, hf8 b, f32x16 c) {
    return __builtin_amdgcn_mfma_f32_32x32x16_f16(a, b, c, 0, 0, 0);
}
__device__ __forceinline__ unsigned pk2(float a, float b) {
    return __builtin_bit_cast(unsigned, __builtin_amdgcn_cvt_pkrtz(a, b));
}
__device__ __forceinline__ unsigned pk2_relu(float a, float b) {
    return __builtin_bit_cast(unsigned,
        __builtin_amdgcn_cvt_pkrtz(fmaxf(a, 0.f), fmaxf(b, 0.f)));
}

// hidden-layer A fragment (IN=40 + bias at k=40)
template<int IN, int OUT>
__device__ hf8 load_wfrag(const float* __restrict__ w, const float* __restrict__ b,
                          int mt, int ks, int lane) {
    const int r = mt * 32 + (lane & 31);
    const int kbase = ks * 16 + ((lane >> 5) & 1) * 8;
    hf8 f;
#pragma unroll
    for (int j = 0; j < 8; ++j) {
        const int k = kbase + j;
        float v = 0.f;
        if (r < OUT) {
            if (k < IN) v = w[r * IN + k];
            else if (k == IN) v = b[r];
        }
        f[j] = (__fp16)v;
    }
    return f;
}

// layer-1 A fragment with padded K map (IN fixed at 10)
template<int OUT>
__device__ hf8 load_wfrag_l1(const float* __restrict__ w, const float* __restrict__ b,
                             int mt, int lane) {
    const int r = mt * 32 + (lane & 31);
    const int kbase = ((lane >> 5) & 1) * 8;
    hf8 f;
#pragma unroll
    for (int j = 0; j < 8; ++j) {
        const int k = kbase + j;
        float v = 0.f;
        if (r < OUT) {
            int src = -1;
            if (k < 3) src = k;                       // xd
            else if (k >= 4 && k < 7) src = k - 1;    // xs
            else if (k >= 8 && k < 12) src = k - 2;   // ea/msg
            if (src >= 0) v = w[r * 10 + src];
            else if (k == 12) v = b[r];
        }
        f[j] = (__fp16)v;
    }
    return f;
}

#define LGKM0() do { asm volatile("s_waitcnt lgkmcnt(0)" ::: "memory"); \
                     __builtin_amdgcn_sched_barrier(0); } while (0)

#define WRITE_T0(ACC) do { \
    _Float16* wrb = myrow + 4 * hi; \
    _Pragma("unroll") \
    for (int q = 0; q < 4; ++q) { \
        uint2 v; v.x = pk2_relu((ACC)[4*q+0], (ACC)[4*q+1]); \
                 v.y = pk2_relu((ACC)[4*q+2], (ACC)[4*q+3]); \
        *(uint2*)(wrb + 8 * q) = v; \
    } } while (0)
#define WRITE_T1(ACC) do { \
    uint2 v; v.x = pk2_relu((ACC)[0], (ACC)[1]); \
             v.y = pk2_relu((ACC)[2], (ACC)[3]); \
    *(uint2*)(myrow + 32 + 4 * hi) = v; \
    if (hi == 0) *(unsigned*)(myrow + 40) = 0x00003c00u; /* {1.0h, 0h} */ \
    } while (0)

template<bool IS_MSG>
__global__ __launch_bounds__(256) void edge_kernel(
    const uint2* __restrict__ nodef,  // packed f16x4 node feats (msg: x; out: xt)
    const int*   __restrict__ ei,
    const void*  __restrict__ eattr,  // msg: ea f32[E,4];  out: emsg uint2[E]
    const float* __restrict__ w1, const float* __restrict__ b1,
    const float* __restrict__ w2, const float* __restrict__ b2,
    const float* __restrict__ w3, const float* __restrict__ b3,
    _Float16* __restrict__ emsg_out,  // msg only
    float* __restrict__ out,          // out only
    int n_edges)
{
    __shared__ _Float16 sh[4][NEPC * PITCH];
    const int lane = threadIdx.x & 63;
    const int widx = threadIdx.x >> 6;
    _Float16* row0 = sh[widx];

    hf8 wa1[2], wa2[2][3], wa3[3];
#pragma unroll
    for (int t = 0; t < 2; ++t) wa1[t] = load_wfrag_l1<40>(w1, b1, t, lane);
#pragma unroll
    for (int t = 0; t < 2; ++t)
#pragma unroll
        for (int s = 0; s < 3; ++s) wa2[t][s] = load_wfrag<40, 40>(w2, b2, t, s, lane);
#pragma unroll
    for (int s = 0; s < 3; ++s)
        wa3[s] = load_wfrag<40, (IS_MSG ? 4 : 1)>(w3, b3, 0, s, lane);

    // one-time zero of the wave's buffer (covers pad slots 41..47 etc.)
    for (int i = lane; i < NEPC * PITCH; i += 64) row0[i] = (_Float16)0.f;
    LGKM0();

    const int gwave = (int)((blockIdx.x * blockDim.x + threadIdx.x) >> 6);
    const int nwave = (int)((gridDim.x * blockDim.x) >> 6);
    const int nchunk = (n_edges + NEPC - 1) / NEPC;

    const int el = lane >> 1, half_ = lane & 1;  // staging: 2 lanes per edge
    const int ecol = lane & 31;                  // MFMA column edge
    const int hi = lane >> 5;
    _Float16* myrow = row0 + ecol * PITCH;
    const _Float16* brow = myrow + hi * 8;
    _Float16* wrow = row0 + el * PITCH;

    int c = gwave;
    if (c >= nchunk) return;
    const int last = n_edges - 1;
    auto eclamp = [&](int cc) { int e = cc * NEPC + el; return e < last ? e : last; };

    // ---- prologue: stage chunk c, prefetch idx for c+nwave ----
    uint2 stA = make_uint2(0u, 0u);
    uint2 stB = make_uint2(0x00003c00u, 0u);     // odd lanes: bias words
    float4 eaR = make_float4(0.f, 0.f, 0.f, 0.f);
    int sN = 0, dN = 0;
    {
        const int e0c = eclamp(c);
        if (half_ == 0) {
            const int s0 = ei[e0c], d0 = ei[n_edges + e0c];
            stA = nodef[d0]; stB = nodef[s0];
        } else {
            if (IS_MSG) eaR = ((const float4*)eattr)[e0c];
            else        stA = ((const uint2*)eattr)[e0c];
        }
        const int e1c = eclamp(c + nwave);
        if (half_ == 0) { sN = ei[e1c]; dN = ei[n_edges + e1c]; }
    }

    for (; c < nchunk; ) {
        const int cn = c + nwave;

        // (1) write staged registers -> LDS input slots
        if (half_ == 0) {
            *(uint2*)(wrow + 0) = stA;          // slots 0-3: xd
            *(uint2*)(wrow + 4) = stB;          // slots 4-7: xs
        } else {
            uint2 w;
            if (IS_MSG) { w.x = pk2(eaR.x, eaR.y); w.y = pk2(eaR.z, eaR.w); }
            else        w = stA;
            *(uint2*)(wrow + 8)  = w;           // slots 8-11: ea/msg
            *(uint2*)(wrow + 12) = stB;         // slots 12-15: bias,0,0,0
        }
        LGKM0();

        // (2) issue feature gathers for chunk cn (idx prefetched last iter)
        // (3) issue idx loads for chunk cn+nwave
        uint2 nA = stA, nB = stB; float4 eaN = eaR; int sN2 = sN, dN2 = dN;
        {
            if (half_ == 0) { nA = nodef[dN]; nB = nodef[sN]; }
            else if (IS_MSG) eaN = ((const float4*)eattr)[eclamp(cn)];
            else             nA = ((const uint2*)eattr)[eclamp(cn)];
            const int e2c = eclamp(cn + nwave);
            if (half_ == 0) { sN2 = ei[e2c]; dN2 = ei[n_edges + e2c]; }
        }

        // (4) layer 1: K=16 padded input
        f32x16 a0 = {}, a1 = {};
        {
            hf8 bf = *(const hf8*)(brow);
            a0 = mfma16(wa1[0], bf, a0);
            a1 = mfma16(wa1[1], bf, a1);
        }
        __builtin_amdgcn_sched_barrier(0);
        WRITE_T0(a0);
        WRITE_T1(a1);
        LGKM0();

        // layer 2: K=48 (ch 0..39 + bias@40)
        f32x16 c0 = {}, c1 = {};
        {
            hf8 b0v = *(const hf8*)(brow);
            hf8 b1v = *(const hf8*)(brow + 16);
            hf8 b2v = *(const hf8*)(brow + 32);
            c0 = mfma16(wa2[0][0], b0v, c0); c1 = mfma16(wa2[1][0], b0v, c1);
            c0 = mfma16(wa2[0][1], b1v, c0); c1 = mfma16(wa2[1][1], b1v, c1);
            c0 = mfma16(wa2[0][2], b2v, c0); c1 = mfma16(wa2[1][2], b2v, c1);
        }
        __builtin_amdgcn_sched_barrier(0);
        WRITE_T0(c0);
        WRITE_T1(c1);
        LGKM0();

        // layer 3: K=48, M-tile 0 only
        f32x16 z0 = {};
        {
            hf8 b0v = *(const hf8*)(brow);
            hf8 b1v = *(const hf8*)(brow + 16);
            hf8 b2v = *(const hf8*)(brow + 32);
            z0 = mfma16(wa3[0], b0v, z0);
            z0 = mfma16(wa3[1], b1v, z0);
            z0 = mfma16(wa3[2], b2v, z0);
        }

        // (5) head
        if (hi == 0) {
            const int e = c * NEPC + ecol;
            if (e < n_edges) {
                if (IS_MSG) {
                    *(uint2*)(emsg_out + (size_t)e * 4) =
                        make_uint2(pk2(z0[0], z0[1]), pk2(z0[2], z0[3]));
                } else {
                    out[e] = 1.f / (1.f + expf(-z0[0]));
                }
            }
        }

        // (6) rotate pipeline registers
        stA = nA; stB = nB; eaR = eaN; sN = sN2; dN = dN2;
        c = cn;
    }
}

// ---- node feature packing: x f32[N,3] -> uint2 {pk(x0,x1), pk(x2,0)} ----
__global__ __launch_bounds__(256) void nodef_kernel(
    const float* __restrict__ x, uint2* __restrict__ nodef, int n_nodes)
{
    int n = blockIdx.x * blockDim.x + threadIdx.x;
    if (n >= n_nodes) return;
    nodef[n] = make_uint2(pk2(x[n * 3 + 0], x[n * 3 + 1]), pk2(x[n * 3 + 2], 0.f));
}

// ---- aggregation phase 1 ----
__device__ __forceinline__ void bin_accum(float* __restrict__ bin, int bbase, int d,
                                          const uint2* __restrict__ emsg, long long e) {
    const unsigned nl = (unsigned)(d - bbase);
    if (nl < (unsigned)BS) {
        const uint2 mv = emsg[e];
        f16x2 lo = __builtin_bit_cast(f16x2, mv.x);
        f16x2 hi = __builtin_bit_cast(f16x2, mv.y);
        float* p = bin + nl * 4;
        atomicAdd(p + 0, (float)lo.x);
        atomicAdd(p + 1, (float)lo.y);
        atomicAdd(p + 2, (float)hi.x);
        atomicAdd(p + 3, (float)hi.y);
    }
}

__global__ __launch_bounds__(1024) void bin_kernel(
    const int* __restrict__ ei,
    const uint2* __restrict__ emsg,
    float* __restrict__ scratch,      // [B*nw][BS*4]
    int n_edges, int nw)
{
    __shared__ float bin[BS * 4];     // 64 KB
    const int B = gridDim.x / nw;
    const int wchunk = blockIdx.x / B;
    const int b = blockIdx.x % B;
    const int bbase = b * BS;
    const int tid = threadIdx.x;

#pragma unroll
    for (int i = 0; i < (BS * 4) / 1024; ++i)
        bin[tid + i * 1024] = 0.f;
    __syncthreads();

    long long e0 = ((long long)n_edges * wchunk / nw) & ~3LL;
    long long e1 = (wchunk == nw - 1) ? (long long)n_edges
                                      : (((long long)n_edges * (wchunk + 1) / nw) & ~3LL);
    const long long nfull = (e1 - e0) >> 2;
    const int* dstp = ei + n_edges;

    for (long long g = tid; g < nfull; g += 1024) {
        const long long e = e0 + g * 4;
        const int4 d4 = *(const int4*)(dstp + e);
        bin_accum(bin, bbase, d4.x, emsg, e + 0);
        bin_accum(bin, bbase, d4.y, emsg, e + 1);
        bin_accum(bin, bbase, d4.z, emsg, e + 2);
        bin_accum(bin, bbase, d4.w, emsg, e + 3);
    }
    for (long long e = e0 + nfull * 4 + tid; e < e1; e += 1024)
        bin_accum(bin, bbase, dstp[e], emsg, e);

    __syncthreads();

    float4* dst = (float4*)(scratch + ((size_t)(b * nw + wchunk)) * BS * 4);
    const float4* srcb = (const float4*)bin;
#pragma unroll
    for (int i = 0; i < (BS * 4) / 4 / 1024; ++i)
        dst[tid + i * 1024] = srcb[tid + i * 1024];
}

// ---- aggregation phase 2 ----
__global__ __launch_bounds__(256) void reduce_kernel(
    const float* __restrict__ scratch,
    float* __restrict__ aggr,
    int n_nodes, int nw)
{
    int n = blockIdx.x * blockDim.x + threadIdx.x;
    if (n >= n_nodes) return;
    const int b = n / BS, nl = n % BS;
    float4 acc = make_float4(0.f, 0.f, 0.f, 0.f);
    for (int w = 0; w < nw; ++w) {
        const float4 v = *(const float4*)(scratch + ((size_t)(b * nw + w) * BS + nl) * 4);
        acc.x += v.x; acc.y += v.y; acc.z += v.z; acc.w += v.w;
    }
    *(float4*)(aggr + (size_t)n * 4) = acc;
}

template<int IN, int OUT, bool RELU>
__device__ __forceinline__ void dense(const float* __restrict__ w,
                                      const float* __restrict__ b,
                                      const float* in, float* out) {
#pragma unroll
    for (int j = 0; j < OUT; ++j) {
        float acc = b[j];
#pragma unroll
        for (int k = 0; k < IN; ++k) acc = fmaf(w[j * IN + k], in[k], acc);
        out[j] = RELU ? fmaxf(acc, 0.f) : acc;
    }
}

__global__ __launch_bounds__(256) void node_kernel(
    const float* __restrict__ x,
    const float* __restrict__ aggr,
    const float* __restrict__ w1, const float* __restrict__ b1,
    const float* __restrict__ w2, const float* __restrict__ b2,
    const float* __restrict__ w3, const float* __restrict__ b3,
    uint2* __restrict__ xth,          // packed f16x4 output
    int n_nodes)
{
    int n = blockIdx.x * blockDim.x + threadIdx.x;
    if (n >= n_nodes) return;

    float in[7];
    in[0] = x[n * 3 + 0]; in[1] = x[n * 3 + 1]; in[2] = x[n * 3 + 2];
    const float4 ag = *(const float4*)(aggr + (size_t)n * 4);
    in[3] = ag.x; in[4] = ag.y; in[5] = ag.z; in[6] = ag.w;

    float h1[40], h2[40], o[3];
    dense<7, 40, true >(w1, b1, in, h1);
    dense<40, 40, true>(w2, b2, h1, h2);
    dense<40, 3, false>(w3, b3, h2, o);

    xth[n] = make_uint2(pk2(o[0], o[1]), pk2(o[2], 0.f));
}

extern "C" void kernel_launch(void* const* d_in, const int* in_sizes, int n_in,
                              void* d_out, int out_size, void* d_ws, size_t ws_size,
                              hipStream_t stream) {
    const float* x  = (const float*)d_in[0];
    const int*   ei = (const int*)d_in[1];   // int64 delivered as int32
    const float* ea = (const float*)d_in[2];

    const float* r1_w1 = (const float*)d_in[3];
    const float* r1_b1 = (const float*)d_in[4];
    const float* r1_w2 = (const float*)d_in[5];
    const float* r1_b2 = (const float*)d_in[6];
    const float* r1_w3 = (const float*)d_in[7];
    const float* r1_b3 = (const float*)d_in[8];

    const float* o_w1 = (const float*)d_in[9];
    const float* o_b1 = (const float*)d_in[10];
    const float* o_w2 = (const float*)d_in[11];
    const float* o_b2 = (const float*)d_in[12];
    const float* o_w3 = (const float*)d_in[13];
    const float* o_b3 = (const float*)d_in[14];

    const float* r2_w1 = (const float*)d_in[15];
    const float* r2_b1 = (const float*)d_in[16];
    const float* r2_w2 = (const float*)d_in[17];
    const float* r2_b2 = (const float*)d_in[18];
    const float* r2_w3 = (const float*)d_in[19];
    const float* r2_b3 = (const float*)d_in[20];

    const int n_nodes = in_sizes[0] / 3;
    const int n_edges = in_sizes[2] / 4;
    const int B = (n_nodes + BS - 1) / BS;

    // ws: nodef uint2[N] | aggr f32[N*4] | emsg f16[E*4] | scratch f32[B*nw*BS*4]
    uint2*    nodef   = (uint2*)d_ws;
    float*    aggr    = (float*)(nodef + n_nodes);
    _Float16* emsg    = (_Float16*)(aggr + (size_t)n_nodes * 4);
    float*    scratch = (float*)(emsg + (size_t)n_edges * 4);

    const size_t fixed_bytes = (size_t)n_nodes * 8 + (size_t)n_nodes * 16
                             + (size_t)n_edges * 8;
    int nw = 16;
    if (ws_size < fixed_bytes + (size_t)B * nw * BS * 4 * sizeof(float)) nw = 8;

    const int eb = 2048;
    const int nb = (n_nodes + 255) / 256;

    nodef_kernel<<<nb, 256, 0, stream>>>(x, nodef, n_nodes);

    edge_kernel<true><<<eb, 256, 0, stream>>>(nodef, ei, (const void*)ea,
        r1_w1, r1_b1, r1_w2, r1_b2, r1_w3, r1_b3,
        emsg, nullptr, n_edges);

    bin_kernel<<<B * nw, 1024, 0, stream>>>(ei, (const uint2*)emsg, scratch,
                                            n_edges, nw);

    reduce_kernel<<<nb, 256, 0, stream>>>(scratch, aggr, n_nodes, nw);

    node_kernel<<<nb, 256, 0, stream>>>(x, aggr,
        o_w1, o_b1, o_w2, o_b2, o_w3, o_b3, nodef, n_nodes);

    edge_kernel<false><<<eb, 256, 0, stream>>>(nodef, ei, (const void*)emsg,
        r2_w1, r2_b1, r2_w2, r2_b2, r2_w3, r2_b3,
        nullptr, (float*)d_out, n_edges);
}

// Round 9
// 227.461 us; speedup vs baseline: 2.5834x; 1.0350x over previous
//
#include <hip/hip_runtime.h>
#include <math.h>

// Interaction Network — LDS-free MFMA edge kernels, cross-lane layer transitions
// via __shfl_xor(v,32) (ds_bpermute; unambiguous semantics).
//  K0 nodef (nodes): pack x -> f16x4 {x0,x1,x2,0}
//  K1 msg   (edges): emsg = MLP_R1([x[dst],x[src],ea]), mfma_32x32x16_f16,
//           in-register layer transitions, no LDS tile, no barriers.
//  K2 bin   (B x NW blocks): LDS f32 bins; scan edge chunk; flush partials
//  K3 red   (nodes): aggr[n] = sum_w partial[b][w][n]
//  K4 node  (nodes): xt = MLP_O([x, aggr]) -> packed f16x4 (reuses nodef buffer)
//  K5 out   (edges): out = sigmoid(MLP_R2([xt[dst],xt[src],emsg]))
// Layer-1 K layout: k0-2 xd | 3 pad | 4-6 xs | 7 pad | 8-11 ea/msg | 12 bias | 13-15 pad
// C layout (HW-verified by rounds 4-7): col=lane&31, row=(reg&3)+8*(reg>>2)+4*(lane>>5).
// All 40 channels of edge e live in lane pair {e, e+32}; partner words fetched
// with shfl_xor 32, then hi/lo selects rebuild the next layer's B fragments.

typedef __fp16 hf8 __attribute__((ext_vector_type(8)));
typedef _Float16 f16x2 __attribute__((ext_vector_type(2)));
typedef float f32x16 __attribute__((ext_vector_type(16)));
typedef unsigned u32x4 __attribute__((ext_vector_type(4)));

#define NEPC  32   // edges per wave-chunk (one MFMA column tile)
#define BS    4096 // nodes per aggregation bin

__device__ __forceinline__ f32x16 mfma16(hf8 a, hf8 b, f32x16 c) {
    return __builtin_amdgcn_mfma_f32_32x32x16_f16(a, b, c, 0, 0, 0);
}
__device__ __forceinline__ unsigned pk2(float a, float b) {
    return __builtin_bit_cast(unsigned, __builtin_amdgcn_cvt_pkrtz(a, b));
}
__device__ __forceinline__ unsigned pk2_relu(float a, float b) {
    return __builtin_bit_cast(unsigned,
        __builtin_amdgcn_cvt_pkrtz(fmaxf(a, 0.f), fmaxf(b, 0.f)));
}
__device__ __forceinline__ unsigned pswap(unsigned v) {
    return (unsigned)__shfl_xor((int)v, 32, 64);   // partner lane = lane ^ 32
}
__device__ __forceinline__ hf8 frag_from(unsigned a, unsigned b, unsigned c, unsigned d) {
    u32x4 v = {a, b, c, d};
    return __builtin_bit_cast(hf8, v);
}

// Build the 3 B-fragments (K=48: ch0..39 + bias@40) for the next layer from
// C-layout accumulators t0 (ch 0..31) and t1 (ch 32..39), relu applied.
// Word wj on a LO lane holds ch{2j,2j+1} of {0..3,8..11,16..19,24..27};
// on a HI lane ch of {4..7,12..15,20..23,28..31}; w8/w9: tile-1 rows.
__device__ __forceinline__ void build_frags(const f32x16& t0, const f32x16& t1,
                                            int hi, hf8& F0, hf8& F1, hf8& F2) {
    const unsigned w0 = pk2_relu(t0[0],  t0[1]);
    const unsigned w1 = pk2_relu(t0[2],  t0[3]);
    const unsigned w2 = pk2_relu(t0[4],  t0[5]);
    const unsigned w3 = pk2_relu(t0[6],  t0[7]);
    const unsigned w4 = pk2_relu(t0[8],  t0[9]);
    const unsigned w5 = pk2_relu(t0[10], t0[11]);
    const unsigned w6 = pk2_relu(t0[12], t0[13]);
    const unsigned w7 = pk2_relu(t0[14], t0[15]);
    const unsigned w8 = pk2_relu(t1[0],  t1[1]);
    const unsigned w9 = pk2_relu(t1[2],  t1[3]);
    const unsigned p0 = pswap(w0), p1 = pswap(w1), p2 = pswap(w2), p3 = pswap(w3);
    const unsigned p4 = pswap(w4), p5 = pswap(w5), p6 = pswap(w6), p7 = pswap(w7);
    const unsigned p8 = pswap(w8), p9 = pswap(w9);
    // F0: k 0..15.  lo: [ch0,1|2,3|4,5|6,7] = [w0,w1,p0,p1]
    //               hi: [ch8,9|10,11|12,13|14,15] = [p2,p3,w2,w3]
    F0 = frag_from(hi ? p2 : w0, hi ? p3 : w1, hi ? w2 : p0, hi ? w3 : p1);
    // F1: k 16..31. lo: [w4,w5,p4,p5]  hi: [p6,p7,w6,w7]
    F1 = frag_from(hi ? p6 : w4, hi ? p7 : w5, hi ? w6 : p4, hi ? w7 : p5);
    // F2: k 32..47. lo: [ch32,33|34,35|36,37|38,39] = [w8,w9,p8,p9]
    //               hi: [bias1.0,0|0|0|0]
    F2 = frag_from(hi ? 0x00003c00u : w8, hi ? 0u : w9, hi ? 0u : p8, hi ? 0u : p9);
}

// hidden-layer A fragment (IN=40 + bias at k=40)
template<int IN, int OUT>
__device__ hf8 load_wfrag(const float* __restrict__ w, const float* __restrict__ b,
                          int mt, int ks, int lane) {
    const int r = mt * 32 + (lane & 31);
    const int kbase = ks * 16 + ((lane >> 5) & 1) * 8;
    hf8 f;
#pragma unroll
    for (int j = 0; j < 8; ++j) {
        const int k = kbase + j;
        float v = 0.f;
        if (r < OUT) {
            if (k < IN) v = w[r * IN + k];
            else if (k == IN) v = b[r];
        }
        f[j] = (__fp16)v;
    }
    return f;
}

// layer-1 A fragment, padded K map (IN fixed at 10)
template<int OUT>
__device__ hf8 load_wfrag_l1(const float* __restrict__ w, const float* __restrict__ b,
                             int mt, int lane) {
    const int r = mt * 32 + (lane & 31);
    const int kbase = ((lane >> 5) & 1) * 8;
    hf8 f;
#pragma unroll
    for (int j = 0; j < 8; ++j) {
        const int k = kbase + j;
        float v = 0.f;
        if (r < OUT) {
            int src = -1;
            if (k < 3) src = k;                       // xd
            else if (k >= 4 && k < 7) src = k - 1;    // xs
            else if (k >= 8 && k < 12) src = k - 2;   // ea/msg
            if (src >= 0) v = w[r * 10 + src];
            else if (k == 12) v = b[r];
        }
        f[j] = (__fp16)v;
    }
    return f;
}

template<bool IS_MSG>
__global__ __launch_bounds__(256) void edge_kernel(
    const uint2* __restrict__ nodef,  // packed f16x4 node feats (msg: x; out: xt)
    const int*   __restrict__ ei,
    const void*  __restrict__ eattr,  // msg: ea f32[E,4];  out: emsg uint2[E]
    const float* __restrict__ w1, const float* __restrict__ b1,
    const float* __restrict__ w2, const float* __restrict__ b2,
    const float* __restrict__ w3, const float* __restrict__ b3,
    uint2* __restrict__ emsg_out,     // msg only
    float* __restrict__ out,          // out only
    int n_edges)
{
    const int lane = threadIdx.x & 63;
    const int ecol = lane & 31;
    const int hi = lane >> 5;

    hf8 wa1[2], wa2[2][3], wa3[3];
#pragma unroll
    for (int t = 0; t < 2; ++t) wa1[t] = load_wfrag_l1<40>(w1, b1, t, lane);
#pragma unroll
    for (int t = 0; t < 2; ++t)
#pragma unroll
        for (int s = 0; s < 3; ++s) wa2[t][s] = load_wfrag<40, 40>(w2, b2, t, s, lane);
#pragma unroll
    for (int s = 0; s < 3; ++s)
        wa3[s] = load_wfrag<40, (IS_MSG ? 4 : 1)>(w3, b3, 0, s, lane);

    const int gwave = (int)((blockIdx.x * blockDim.x + threadIdx.x) >> 6);
    const int nwave = (int)((gridDim.x * blockDim.x) >> 6);
    const int nchunk = (n_edges + NEPC - 1) / NEPC;
    const int last = n_edges - 1;

    int c = gwave;
    if (c >= nchunk) return;
    auto eclamp = [&](int cc) { int e = cc * NEPC + ecol; return e < last ? e : last; };

    // ---- prologue: stage features for chunk c; prefetch indices for c+nwave ----
    uint2 fA, fB;
    int sN = 0, dN = 0;
    {
        const int e = eclamp(c);
        if (hi == 0) {
            const int s = ei[e], d = ei[n_edges + e];
            fA = nodef[d]; fB = nodef[s];
            const int e2 = eclamp(c + nwave);
            sN = ei[e2]; dN = ei[n_edges + e2];
        } else {
            if (IS_MSG) {
                const float4 ev = ((const float4*)eattr)[e];
                fA = make_uint2(pk2(ev.x, ev.y), pk2(ev.z, ev.w));
            } else {
                fA = ((const uint2*)eattr)[e];
            }
            fB = make_uint2(0x00003c00u, 0u);   // bias word {1.0h, 0h}
        }
    }

    for (; c < nchunk; ) {
        const int cn = c + nwave;

        // layer-1 B fragment from staged registers (no LDS)
        const hf8 bf = frag_from(fA.x, fA.y, fB.x, fB.y);

        // prefetch next chunk (features via last iter's indices; indices for cn+nwave)
        uint2 nfA = fA, nfB = fB;
        int sP = sN, dP = dN;
        {
            if (hi == 0) {
                nfA = nodef[dN]; nfB = nodef[sN];
                const int e3 = eclamp(cn + nwave);
                sP = ei[e3]; dP = ei[n_edges + e3];
            } else {
                const int e2 = eclamp(cn);
                if (IS_MSG) {
                    const float4 ev = ((const float4*)eattr)[e2];
                    nfA = make_uint2(pk2(ev.x, ev.y), pk2(ev.z, ev.w));
                } else {
                    nfA = ((const uint2*)eattr)[e2];
                }
            }
        }

        // layer 1 (K=16 padded input)
        f32x16 a0 = {}, a1 = {};
        a0 = mfma16(wa1[0], bf, a0);
        a1 = mfma16(wa1[1], bf, a1);

        // transition 1 (in-register transpose via shfl_xor 32)
        hf8 f0, f1, f2;
        build_frags(a0, a1, hi, f0, f1, f2);

        // layer 2 (K=48)
        f32x16 c0 = {}, c1 = {};
        c0 = mfma16(wa2[0][0], f0, c0); c1 = mfma16(wa2[1][0], f0, c1);
        c0 = mfma16(wa2[0][1], f1, c0); c1 = mfma16(wa2[1][1], f1, c1);
        c0 = mfma16(wa2[0][2], f2, c0); c1 = mfma16(wa2[1][2], f2, c1);

        // transition 2
        hf8 g0, g1, g2;
        build_frags(c0, c1, hi, g0, g1, g2);

        // layer 3 (K=48)
        f32x16 z0 = {};
        z0 = mfma16(wa3[0], g0, z0);
        z0 = mfma16(wa3[1], g1, z0);
        z0 = mfma16(wa3[2], g2, z0);

        // head: lanes 0..31 hold channels 0..3 of edge ecol in regs 0..3
        if (hi == 0) {
            const int e = c * NEPC + ecol;
            if (e < n_edges) {
                if (IS_MSG) {
                    emsg_out[e] = make_uint2(pk2(z0[0], z0[1]), pk2(z0[2], z0[3]));
                } else {
                    out[e] = 1.f / (1.f + expf(-z0[0]));
                }
            }
        }

        // rotate pipeline registers
        fA = nfA; fB = nfB; sN = sP; dN = dP;
        c = cn;
    }
}

// ---- node feature packing: x f32[N,3] -> uint2 {pk(x0,x1), pk(x2,0)} ----
__global__ __launch_bounds__(256) void nodef_kernel(
    const float* __restrict__ x, uint2* __restrict__ nodef, int n_nodes)
{
    int n = blockIdx.x * blockDim.x + threadIdx.x;
    if (n >= n_nodes) return;
    nodef[n] = make_uint2(pk2(x[n * 3 + 0], x[n * 3 + 1]), pk2(x[n * 3 + 2], 0.f));
}

// ---- aggregation phase 1: per-(bin, edge-chunk) LDS accumulation ----
__device__ __forceinline__ void bin_accum(float* __restrict__ bin, int bbase, int d,
                                          const uint2* __restrict__ emsg, long long e) {
    const unsigned nl = (unsigned)(d - bbase);
    if (nl < (unsigned)BS) {
        const uint2 mv = emsg[e];
        f16x2 lo = __builtin_bit_cast(f16x2, mv.x);
        f16x2 hi = __builtin_bit_cast(f16x2, mv.y);
        float* p = bin + nl * 4;
        atomicAdd(p + 0, (float)lo.x);
        atomicAdd(p + 1, (float)lo.y);
        atomicAdd(p + 2, (float)hi.x);
        atomicAdd(p + 3, (float)hi.y);
    }
}

__global__ __launch_bounds__(1024) void bin_kernel(
    const int* __restrict__ ei,
    const uint2* __restrict__ emsg,
    float* __restrict__ scratch,      // [B*nw][BS*4]
    int n_edges, int nw)
{
    __shared__ float bin[BS * 4];     // 64 KB
    const int B = gridDim.x / nw;
    const int wchunk = blockIdx.x / B;
    const int b = blockIdx.x % B;
    const int bbase = b * BS;
    const int tid = threadIdx.x;

#pragma unroll
    for (int i = 0; i < (BS * 4) / 1024; ++i)
        bin[tid + i * 1024] = 0.f;
    __syncthreads();

    long long e0 = ((long long)n_edges * wchunk / nw) & ~3LL;
    long long e1 = (wchunk == nw - 1) ? (long long)n_edges
                                      : (((long long)n_edges * (wchunk + 1) / nw) & ~3LL);
    const long long nfull = (e1 - e0) >> 2;
    const int* dstp = ei + n_edges;

    for (long long g = tid; g < nfull; g += 1024) {
        const long long e = e0 + g * 4;
        const int4 d4 = *(const int4*)(dstp + e);
        bin_accum(bin, bbase, d4.x, emsg, e + 0);
        bin_accum(bin, bbase, d4.y, emsg, e + 1);
        bin_accum(bin, bbase, d4.z, emsg, e + 2);
        bin_accum(bin, bbase, d4.w, emsg, e + 3);
    }
    for (long long e = e0 + nfull * 4 + tid; e < e1; e += 1024)
        bin_accum(bin, bbase, dstp[e], emsg, e);

    __syncthreads();

    float4* dst = (float4*)(scratch + ((size_t)(b * nw + wchunk)) * BS * 4);
    const float4* srcb = (const float4*)bin;
#pragma unroll
    for (int i = 0; i < (BS * 4) / 4 / 1024; ++i)
        dst[tid + i * 1024] = srcb[tid + i * 1024];
}

// ---- aggregation phase 2: sum chunk partials -> aggr f32[N][4] ----
__global__ __launch_bounds__(256) void reduce_kernel(
    const float* __restrict__ scratch,
    float* __restrict__ aggr,
    int n_nodes, int nw)
{
    int n = blockIdx.x * blockDim.x + threadIdx.x;
    if (n >= n_nodes) return;
    const int b = n / BS, nl = n % BS;
    float4 acc = make_float4(0.f, 0.f, 0.f, 0.f);
    for (int w = 0; w < nw; ++w) {
        const float4 v = *(const float4*)(scratch + ((size_t)(b * nw + w) * BS + nl) * 4);
        acc.x += v.x; acc.y += v.y; acc.z += v.z; acc.w += v.w;
    }
    *(float4*)(aggr + (size_t)n * 4) = acc;
}

template<int IN, int OUT, bool RELU>
__device__ __forceinline__ void dense(const float* __restrict__ w,
                                      const float* __restrict__ b,
                                      const float* in, float* out) {
#pragma unroll
    for (int j = 0; j < OUT; ++j) {
        float acc = b[j];
#pragma unroll
        for (int k = 0; k < IN; ++k) acc = fmaf(w[j * IN + k], in[k], acc);
        out[j] = RELU ? fmaxf(acc, 0.f) : acc;
    }
}

__global__ __launch_bounds__(256) void node_kernel(
    const float* __restrict__ x,
    const float* __restrict__ aggr,
    const float* __restrict__ w1, const float* __restrict__ b1,
    const float* __restrict__ w2, const float* __restrict__ b2,
    const float* __restrict__ w3, const float* __restrict__ b3,
    uint2* __restrict__ xth,          // packed f16x4 output
    int n_nodes)
{
    int n = blockIdx.x * blockDim.x + threadIdx.x;
    if (n >= n_nodes) return;

    float in[7];
    in[0] = x[n * 3 + 0]; in[1] = x[n * 3 + 1]; in[2] = x[n * 3 + 2];
    const float4 ag = *(const float4*)(aggr + (size_t)n * 4);
    in[3] = ag.x; in[4] = ag.y; in[5] = ag.z; in[6] = ag.w;

    float h1[40], h2[40], o[3];
    dense<7, 40, true >(w1, b1, in, h1);
    dense<40, 40, true>(w2, b2, h1, h2);
    dense<40, 3, false>(w3, b3, h2, o);

    xth[n] = make_uint2(pk2(o[0], o[1]), pk2(o[2], 0.f));
}

extern "C" void kernel_launch(void* const* d_in, const int* in_sizes, int n_in,
                              void* d_out, int out_size, void* d_ws, size_t ws_size,
                              hipStream_t stream) {
    const float* x  = (const float*)d_in[0];
    const int*   ei = (const int*)d_in[1];   // int64 delivered as int32
    const float* ea = (const float*)d_in[2];

    const float* r1_w1 = (const float*)d_in[3];
    const float* r1_b1 = (const float*)d_in[4];
    const float* r1_w2 = (const float*)d_in[5];
    const float* r1_b2 = (const float*)d_in[6];
    const float* r1_w3 = (const float*)d_in[7];
    const float* r1_b3 = (const float*)d_in[8];

    const float* o_w1 = (const float*)d_in[9];
    const float* o_b1 = (const float*)d_in[10];
    const float* o_w2 = (const float*)d_in[11];
    const float* o_b2 = (const float*)d_in[12];
    const float* o_w3 = (const float*)d_in[13];
    const float* o_b3 = (const float*)d_in[14];

    const float* r2_w1 = (const float*)d_in[15];
    const float* r2_b1 = (const float*)d_in[16];
    const float* r2_w2 = (const float*)d_in[17];
    const float* r2_b2 = (const float*)d_in[18];
    const float* r2_w3 = (const float*)d_in[19];
    const float* r2_b3 = (const float*)d_in[20];

    const int n_nodes = in_sizes[0] / 3;
    const int n_edges = in_sizes[2] / 4;
    const int B = (n_nodes + BS - 1) / BS;

    // ws: nodef uint2[N] | aggr f32[N*4] | emsg uint2[E] | scratch f32[B*nw*BS*4]
    uint2* nodef   = (uint2*)d_ws;
    float* aggr    = (float*)(nodef + n_nodes);
    uint2* emsg    = (uint2*)(aggr + (size_t)n_nodes * 4);
    float* scratch = (float*)(emsg + n_edges);

    const size_t fixed_bytes = (size_t)n_nodes * 8 + (size_t)n_nodes * 16
                             + (size_t)n_edges * 8;
    int nw = 16;
    if (ws_size < fixed_bytes + (size_t)B * nw * BS * 4 * sizeof(float)) nw = 8;

    const int eb = 2048;
    const int nb = (n_nodes + 255) / 256;

    nodef_kernel<<<nb, 256, 0, stream>>>(x, nodef, n_nodes);

    edge_kernel<true><<<eb, 256, 0, stream>>>(nodef, ei, (const void*)ea,
        r1_w1, r1_b1, r1_w2, r1_b2, r1_w3, r1_b3,
        emsg, nullptr, n_edges);

    bin_kernel<<<B * nw, 1024, 0, stream>>>(ei, emsg, scratch, n_edges, nw);

    reduce_kernel<<<nb, 256, 0, stream>>>(scratch, aggr, n_nodes, nw);

    node_kernel<<<nb, 256, 0, stream>>>(x, aggr,
        o_w1, o_b1, o_w2, o_b2, o_w3, o_b3, nodef, n_nodes);

    edge_kernel<false><<<eb, 256, 0, stream>>>(nodef, ei, (const void*)emsg,
        r2_w1, r2_b1, r2_w2, r2_b2, r2_w3, r2_b3,
        nullptr, (float*)d_out, n_edges);
}

// Round 10
// 195.271 us; speedup vs baseline: 3.0092x; 1.1649x over previous
//
#include <hip/hip_runtime.h>
#include <math.h>

// Interaction Network — LDS-free MFMA edge kernels, ILP x2 (two independent
// 32-edge MFMA column tiles per wave), cross-lane transitions via shfl_xor(32).
//  K0 nodef (nodes): pack x -> f16x4 {x0,x1,x2,0}
//  K1 msg   (edges): emsg = MLP_R1([x[dst],x[src],ea]), mfma_32x32x16_f16
//  K2 bin   (B x NW blocks): LDS f32 bins; scan edge chunk; flush partials
//  K3 red   (nodes): aggr[n] = sum_w partial[b][w][n]
//  K4 node  (nodes): xt = MLP_O([x, aggr]) -> packed f16x4
//  K5 out   (edges): out = sigmoid(MLP_R2([xt[dst],xt[src],emsg]))
// Layer-1 K layout: k0-2 xd | 3 pad | 4-6 xs | 7 pad | 8-11 ea/msg | 12 bias | 13-15 pad
// C layout (HW-verified): col=lane&31, row=(reg&3)+8*(reg>>2)+4*(lane>>5).

typedef __fp16 hf8 __attribute__((ext_vector_type(8)));
typedef _Float16 f16x2 __attribute__((ext_vector_type(2)));
typedef float f32x16 __attribute__((ext_vector_type(16)));
typedef unsigned u32x4 __attribute__((ext_vector_type(4)));

#define NEPC  64   // edges per wave-chunk (two MFMA column tiles X/Y)
#define BS    4096 // nodes per aggregation bin

__device__ __forceinline__ f32x16 mfma16(hf8 a, hf8 b, f32x16 c) {
    return __builtin_amdgcn_mfma_f32_32x32x16_f16(a, b, c, 0, 0, 0);
}
__device__ __forceinline__ unsigned pk2(float a, float b) {
    return __builtin_bit_cast(unsigned, __builtin_amdgcn_cvt_pkrtz(a, b));
}
__device__ __forceinline__ unsigned pk2_relu(float a, float b) {
    return __builtin_bit_cast(unsigned,
        __builtin_amdgcn_cvt_pkrtz(fmaxf(a, 0.f), fmaxf(b, 0.f)));
}
__device__ __forceinline__ unsigned pswap(unsigned v) {
    return (unsigned)__shfl_xor((int)v, 32, 64);   // partner lane = lane ^ 32
}
__device__ __forceinline__ hf8 frag_from(unsigned a, unsigned b, unsigned c, unsigned d) {
    u32x4 v = {a, b, c, d};
    return __builtin_bit_cast(hf8, v);
}

// Build the 3 B-fragments (K=48: ch0..39 + bias@40) from C-layout accumulators
// t0 (ch 0..31) and t1 (ch 32..39), relu applied.
__device__ __forceinline__ void build_frags(const f32x16& t0, const f32x16& t1,
                                            int hi, hf8& F0, hf8& F1, hf8& F2) {
    const unsigned w0 = pk2_relu(t0[0],  t0[1]);
    const unsigned w1 = pk2_relu(t0[2],  t0[3]);
    const unsigned w2 = pk2_relu(t0[4],  t0[5]);
    const unsigned w3 = pk2_relu(t0[6],  t0[7]);
    const unsigned w4 = pk2_relu(t0[8],  t0[9]);
    const unsigned w5 = pk2_relu(t0[10], t0[11]);
    const unsigned w6 = pk2_relu(t0[12], t0[13]);
    const unsigned w7 = pk2_relu(t0[14], t0[15]);
    const unsigned w8 = pk2_relu(t1[0],  t1[1]);
    const unsigned w9 = pk2_relu(t1[2],  t1[3]);
    const unsigned p0 = pswap(w0), p1 = pswap(w1), p2 = pswap(w2), p3 = pswap(w3);
    const unsigned p4 = pswap(w4), p5 = pswap(w5), p6 = pswap(w6), p7 = pswap(w7);
    const unsigned p8 = pswap(w8), p9 = pswap(w9);
    F0 = frag_from(hi ? p2 : w0, hi ? p3 : w1, hi ? w2 : p0, hi ? w3 : p1);
    F1 = frag_from(hi ? p6 : w4, hi ? p7 : w5, hi ? w6 : p4, hi ? w7 : p5);
    F2 = frag_from(hi ? 0x00003c00u : w8, hi ? 0u : w9, hi ? 0u : p8, hi ? 0u : p9);
}

// hidden-layer A fragment (IN=40 + bias at k=40)
template<int IN, int OUT>
__device__ hf8 load_wfrag(const float* __restrict__ w, const float* __restrict__ b,
                          int mt, int ks, int lane) {
    const int r = mt * 32 + (lane & 31);
    const int kbase = ks * 16 + ((lane >> 5) & 1) * 8;
    hf8 f;
#pragma unroll
    for (int j = 0; j < 8; ++j) {
        const int k = kbase + j;
        float v = 0.f;
        if (r < OUT) {
            if (k < IN) v = w[r * IN + k];
            else if (k == IN) v = b[r];
        }
        f[j] = (__fp16)v;
    }
    return f;
}

// layer-1 A fragment, padded K map (IN fixed at 10)
template<int OUT>
__device__ hf8 load_wfrag_l1(const float* __restrict__ w, const float* __restrict__ b,
                             int mt, int lane) {
    const int r = mt * 32 + (lane & 31);
    const int kbase = ((lane >> 5) & 1) * 8;
    hf8 f;
#pragma unroll
    for (int j = 0; j < 8; ++j) {
        const int k = kbase + j;
        float v = 0.f;
        if (r < OUT) {
            int src = -1;
            if (k < 3) src = k;                       // xd
            else if (k >= 4 && k < 7) src = k - 1;    // xs
            else if (k >= 8 && k < 12) src = k - 2;   // ea/msg
            if (src >= 0) v = w[r * 10 + src];
            else if (k == 12) v = b[r];
        }
        f[j] = (__fp16)v;
    }
    return f;
}

template<bool IS_MSG>
__global__ __launch_bounds__(256, 2) void edge_kernel(
    const uint2* __restrict__ nodef,  // packed f16x4 node feats (msg: x; out: xt)
    const int*   __restrict__ ei,
    const void*  __restrict__ eattr,  // msg: ea f32[E,4];  out: emsg uint2[E]
    const float* __restrict__ w1, const float* __restrict__ b1,
    const float* __restrict__ w2, const float* __restrict__ b2,
    const float* __restrict__ w3, const float* __restrict__ b3,
    uint2* __restrict__ emsg_out,     // msg only
    float* __restrict__ out,          // out only
    int n_edges)
{
    const int lane = threadIdx.x & 63;
    const int ecol = lane & 31;
    const int hi = lane >> 5;

    hf8 wa1[2], wa2[2][3], wa3[3];
#pragma unroll
    for (int t = 0; t < 2; ++t) wa1[t] = load_wfrag_l1<40>(w1, b1, t, lane);
#pragma unroll
    for (int t = 0; t < 2; ++t)
#pragma unroll
        for (int s = 0; s < 3; ++s) wa2[t][s] = load_wfrag<40, 40>(w2, b2, t, s, lane);
#pragma unroll
    for (int s = 0; s < 3; ++s)
        wa3[s] = load_wfrag<40, (IS_MSG ? 4 : 1)>(w3, b3, 0, s, lane);

    const int gwave = (int)((blockIdx.x * blockDim.x + threadIdx.x) >> 6);
    const int nwave = (int)((gridDim.x * blockDim.x) >> 6);
    const int nchunk = (n_edges + NEPC - 1) / NEPC;
    const int last = n_edges - 1;

    int c = gwave;
    if (c >= nchunk) return;
    auto eclampX = [&](int cc) { int e = cc * NEPC + ecol;      return e < last ? e : last; };
    auto eclampY = [&](int cc) { int e = cc * NEPC + 32 + ecol; return e < last ? e : last; };

    // ---- prologue: stage features for chunk c; prefetch indices for c+nwave ----
    uint2 fAX, fBX, fAY, fBY;
    int sNX = 0, dNX = 0, sNY = 0, dNY = 0;
    {
        const int eX = eclampX(c), eY = eclampY(c);
        if (hi == 0) {
            const int sX = ei[eX], dX = ei[n_edges + eX];
            const int sY = ei[eY], dY = ei[n_edges + eY];
            fAX = nodef[dX]; fBX = nodef[sX];
            fAY = nodef[dY]; fBY = nodef[sY];
            const int e2X = eclampX(c + nwave), e2Y = eclampY(c + nwave);
            sNX = ei[e2X]; dNX = ei[n_edges + e2X];
            sNY = ei[e2Y]; dNY = ei[n_edges + e2Y];
        } else {
            if (IS_MSG) {
                const float4 evX = ((const float4*)eattr)[eX];
                fAX = make_uint2(pk2(evX.x, evX.y), pk2(evX.z, evX.w));
                const float4 evY = ((const float4*)eattr)[eY];
                fAY = make_uint2(pk2(evY.x, evY.y), pk2(evY.z, evY.w));
            } else {
                fAX = ((const uint2*)eattr)[eX];
                fAY = ((const uint2*)eattr)[eY];
            }
            fBX = make_uint2(0x00003c00u, 0u);   // bias word {1.0h, 0h}
            fBY = fBX;
        }
    }

    for (; c < nchunk; ) {
        const int cn = c + nwave;

        // layer-1 B fragments from staged registers
        const hf8 bfX = frag_from(fAX.x, fAX.y, fBX.x, fBX.y);
        const hf8 bfY = frag_from(fAY.x, fAY.y, fBY.x, fBY.y);

        // prefetch next chunk (features via last iter's indices; indices for cn+nwave)
        uint2 nfAX = fAX, nfBX = fBX, nfAY = fAY, nfBY = fBY;
        int sPX = sNX, dPX = dNX, sPY = sNY, dPY = dNY;
        {
            if (hi == 0) {
                nfAX = nodef[dNX]; nfBX = nodef[sNX];
                nfAY = nodef[dNY]; nfBY = nodef[sNY];
                const int e3X = eclampX(cn + nwave), e3Y = eclampY(cn + nwave);
                sPX = ei[e3X]; dPX = ei[n_edges + e3X];
                sPY = ei[e3Y]; dPY = ei[n_edges + e3Y];
            } else {
                const int e2X = eclampX(cn), e2Y = eclampY(cn);
                if (IS_MSG) {
                    const float4 evX = ((const float4*)eattr)[e2X];
                    nfAX = make_uint2(pk2(evX.x, evX.y), pk2(evX.z, evX.w));
                    const float4 evY = ((const float4*)eattr)[e2Y];
                    nfAY = make_uint2(pk2(evY.x, evY.y), pk2(evY.z, evY.w));
                } else {
                    nfAX = ((const uint2*)eattr)[e2X];
                    nfAY = ((const uint2*)eattr)[e2Y];
                }
            }
        }

        // layer 1 (K=16 padded input) — both tiles
        f32x16 a0X = {}, a1X = {}, a0Y = {}, a1Y = {};
        a0X = mfma16(wa1[0], bfX, a0X);
        a0Y = mfma16(wa1[0], bfY, a0Y);
        a1X = mfma16(wa1[1], bfX, a1X);
        a1Y = mfma16(wa1[1], bfY, a1Y);

        // transition 1 — both tiles (VALU/DS of one overlaps MFMA of the other)
        hf8 f0X, f1X, f2X, f0Y, f1Y, f2Y;
        build_frags(a0X, a1X, hi, f0X, f1X, f2X);
        build_frags(a0Y, a1Y, hi, f0Y, f1Y, f2Y);

        // layer 2 (K=48) — interleaved
        f32x16 c0X = {}, c1X = {}, c0Y = {}, c1Y = {};
        c0X = mfma16(wa2[0][0], f0X, c0X); c0Y = mfma16(wa2[0][0], f0Y, c0Y);
        c1X = mfma16(wa2[1][0], f0X, c1X); c1Y = mfma16(wa2[1][0], f0Y, c1Y);
        c0X = mfma16(wa2[0][1], f1X, c0X); c0Y = mfma16(wa2[0][1], f1Y, c0Y);
        c1X = mfma16(wa2[1][1], f1X, c1X); c1Y = mfma16(wa2[1][1], f1Y, c1Y);
        c0X = mfma16(wa2[0][2], f2X, c0X); c0Y = mfma16(wa2[0][2], f2Y, c0Y);
        c1X = mfma16(wa2[1][2], f2X, c1X); c1Y = mfma16(wa2[1][2], f2Y, c1Y);

        // transition 2 — both tiles
        hf8 g0X, g1X, g2X, g0Y, g1Y, g2Y;
        build_frags(c0X, c1X, hi, g0X, g1X, g2X);
        build_frags(c0Y, c1Y, hi, g0Y, g1Y, g2Y);

        // layer 3 (K=48) — interleaved
        f32x16 z0X = {}, z0Y = {};
        z0X = mfma16(wa3[0], g0X, z0X); z0Y = mfma16(wa3[0], g0Y, z0Y);
        z0X = mfma16(wa3[1], g1X, z0X); z0Y = mfma16(wa3[1], g1Y, z0Y);
        z0X = mfma16(wa3[2], g2X, z0X); z0Y = mfma16(wa3[2], g2Y, z0Y);

        // heads: lanes 0..31 hold channels 0..3 of their edge in regs 0..3
        if (hi == 0) {
            const int eX = c * NEPC + ecol;
            const int eY = eX + 32;
            if (eX < n_edges) {
                if (IS_MSG)
                    emsg_out[eX] = make_uint2(pk2(z0X[0], z0X[1]), pk2(z0X[2], z0X[3]));
                else
                    out[eX] = 1.f / (1.f + expf(-z0X[0]));
            }
            if (eY < n_edges) {
                if (IS_MSG)
                    emsg_out[eY] = make_uint2(pk2(z0Y[0], z0Y[1]), pk2(z0Y[2], z0Y[3]));
                else
                    out[eY] = 1.f / (1.f + expf(-z0Y[0]));
            }
        }

        // rotate pipeline registers
        fAX = nfAX; fBX = nfBX; fAY = nfAY; fBY = nfBY;
        sNX = sPX; dNX = dPX; sNY = sPY; dNY = dPY;
        c = cn;
    }
}

// ---- node feature packing: x f32[N,3] -> uint2 {pk(x0,x1), pk(x2,0)} ----
__global__ __launch_bounds__(256) void nodef_kernel(
    const float* __restrict__ x, uint2* __restrict__ nodef, int n_nodes)
{
    int n = blockIdx.x * blockDim.x + threadIdx.x;
    if (n >= n_nodes) return;
    nodef[n] = make_uint2(pk2(x[n * 3 + 0], x[n * 3 + 1]), pk2(x[n * 3 + 2], 0.f));
}

// ---- aggregation phase 1: per-(bin, edge-chunk) LDS accumulation ----
__device__ __forceinline__ void bin_accum(float* __restrict__ bin, int bbase, int d,
                                          const uint2* __restrict__ emsg, long long e) {
    const unsigned nl = (unsigned)(d - bbase);
    if (nl < (unsigned)BS) {
        const uint2 mv = emsg[e];
        f16x2 lo = __builtin_bit_cast(f16x2, mv.x);
        f16x2 hi = __builtin_bit_cast(f16x2, mv.y);
        float* p = bin + nl * 4;
        atomicAdd(p + 0, (float)lo.x);
        atomicAdd(p + 1, (float)lo.y);
        atomicAdd(p + 2, (float)hi.x);
        atomicAdd(p + 3, (float)hi.y);
    }
}

__global__ __launch_bounds__(1024) void bin_kernel(
    const int* __restrict__ ei,
    const uint2* __restrict__ emsg,
    float* __restrict__ scratch,      // [B*nw][BS*4]
    int n_edges, int nw)
{
    __shared__ float bin[BS * 4];     // 64 KB
    const int B = gridDim.x / nw;
    const int wchunk = blockIdx.x / B;
    const int b = blockIdx.x % B;
    const int bbase = b * BS;
    const int tid = threadIdx.x;

#pragma unroll
    for (int i = 0; i < (BS * 4) / 1024; ++i)
        bin[tid + i * 1024] = 0.f;
    __syncthreads();

    long long e0 = ((long long)n_edges * wchunk / nw) & ~3LL;
    long long e1 = (wchunk == nw - 1) ? (long long)n_edges
                                      : (((long long)n_edges * (wchunk + 1) / nw) & ~3LL);
    const long long nfull = (e1 - e0) >> 2;
    const int* dstp = ei + n_edges;

    for (long long g = tid; g < nfull; g += 1024) {
        const long long e = e0 + g * 4;
        const int4 d4 = *(const int4*)(dstp + e);
        bin_accum(bin, bbase, d4.x, emsg, e + 0);
        bin_accum(bin, bbase, d4.y, emsg, e + 1);
        bin_accum(bin, bbase, d4.z, emsg, e + 2);
        bin_accum(bin, bbase, d4.w, emsg, e + 3);
    }
    for (long long e = e0 + nfull * 4 + tid; e < e1; e += 1024)
        bin_accum(bin, bbase, dstp[e], emsg, e);

    __syncthreads();

    float4* dst = (float4*)(scratch + ((size_t)(b * nw + wchunk)) * BS * 4);
    const float4* srcb = (const float4*)bin;
#pragma unroll
    for (int i = 0; i < (BS * 4) / 4 / 1024; ++i)
        dst[tid + i * 1024] = srcb[tid + i * 1024];
}

// ---- aggregation phase 2: sum chunk partials -> aggr f32[N][4] ----
__global__ __launch_bounds__(256) void reduce_kernel(
    const float* __restrict__ scratch,
    float* __restrict__ aggr,
    int n_nodes, int nw)
{
    int n = blockIdx.x * blockDim.x + threadIdx.x;
    if (n >= n_nodes) return;
    const int b = n / BS, nl = n % BS;
    float4 acc = make_float4(0.f, 0.f, 0.f, 0.f);
    for (int w = 0; w < nw; ++w) {
        const float4 v = *(const float4*)(scratch + ((size_t)(b * nw + w) * BS + nl) * 4);
        acc.x += v.x; acc.y += v.y; acc.z += v.z; acc.w += v.w;
    }
    *(float4*)(aggr + (size_t)n * 4) = acc;
}

template<int IN, int OUT, bool RELU>
__device__ __forceinline__ void dense(const float* __restrict__ w,
                                      const float* __restrict__ b,
                                      const float* in, float* out) {
#pragma unroll
    for (int j = 0; j < OUT; ++j) {
        float acc = b[j];
#pragma unroll
        for (int k = 0; k < IN; ++k) acc = fmaf(w[j * IN + k], in[k], acc);
        out[j] = RELU ? fmaxf(acc, 0.f) : acc;
    }
}

__global__ __launch_bounds__(256) void node_kernel(
    const float* __restrict__ x,
    const float* __restrict__ aggr,
    const float* __restrict__ w1, const float* __restrict__ b1,
    const float* __restrict__ w2, const float* __restrict__ b2,
    const float* __restrict__ w3, const float* __restrict__ b3,
    uint2* __restrict__ xth,          // packed f16x4 output
    int n_nodes)
{
    int n = blockIdx.x * blockDim.x + threadIdx.x;
    if (n >= n_nodes) return;

    float in[7];
    in[0] = x[n * 3 + 0]; in[1] = x[n * 3 + 1]; in[2] = x[n * 3 + 2];
    const float4 ag = *(const float4*)(aggr + (size_t)n * 4);
    in[3] = ag.x; in[4] = ag.y; in[5] = ag.z; in[6] = ag.w;

    float h1[40], h2[40], o[3];
    dense<7, 40, true >(w1, b1, in, h1);
    dense<40, 40, true>(w2, b2, h1, h2);
    dense<40, 3, false>(w3, b3, h2, o);

    xth[n] = make_uint2(pk2(o[0], o[1]), pk2(o[2], 0.f));
}

extern "C" void kernel_launch(void* const* d_in, const int* in_sizes, int n_in,
                              void* d_out, int out_size, void* d_ws, size_t ws_size,
                              hipStream_t stream) {
    const float* x  = (const float*)d_in[0];
    const int*   ei = (const int*)d_in[1];   // int64 delivered as int32
    const float* ea = (const float*)d_in[2];

    const float* r1_w1 = (const float*)d_in[3];
    const float* r1_b1 = (const float*)d_in[4];
    const float* r1_w2 = (const float*)d_in[5];
    const float* r1_b2 = (const float*)d_in[6];
    const float* r1_w3 = (const float*)d_in[7];
    const float* r1_b3 = (const float*)d_in[8];

    const float* o_w1 = (const float*)d_in[9];
    const float* o_b1 = (const float*)d_in[10];
    const float* o_w2 = (const float*)d_in[11];
    const float* o_b2 = (const float*)d_in[12];
    const float* o_w3 = (const float*)d_in[13];
    const float* o_b3 = (const float*)d_in[14];

    const float* r2_w1 = (const float*)d_in[15];
    const float* r2_b1 = (const float*)d_in[16];
    const float* r2_w2 = (const float*)d_in[17];
    const float* r2_b2 = (const float*)d_in[18];
    const float* r2_w3 = (const float*)d_in[19];
    const float* r2_b3 = (const float*)d_in[20];

    const int n_nodes = in_sizes[0] / 3;
    const int n_edges = in_sizes[2] / 4;
    const int B = (n_nodes + BS - 1) / BS;

    // ws: nodef uint2[N] | aggr f32[N*4] | emsg uint2[E] | scratch f32[B*nw*BS*4]
    uint2* nodef   = (uint2*)d_ws;
    float* aggr    = (float*)(nodef + n_nodes);
    uint2* emsg    = (uint2*)(aggr + (size_t)n_nodes * 4);
    float* scratch = (float*)(emsg + n_edges);

    const size_t fixed_bytes = (size_t)n_nodes * 8 + (size_t)n_nodes * 16
                             + (size_t)n_edges * 8;
    int nw = 16;
    if (ws_size < fixed_bytes + (size_t)B * nw * BS * 4 * sizeof(float)) nw = 8;

    const int eb = 512;                 // 2048 waves = exact 2/SIMD residency
    const int nb = (n_nodes + 255) / 256;

    nodef_kernel<<<nb, 256, 0, stream>>>(x, nodef, n_nodes);

    edge_kernel<true><<<eb, 256, 0, stream>>>(nodef, ei, (const void*)ea,
        r1_w1, r1_b1, r1_w2, r1_b2, r1_w3, r1_b3,
        emsg, nullptr, n_edges);

    bin_kernel<<<B * nw, 1024, 0, stream>>>(ei, emsg, scratch, n_edges, nw);

    reduce_kernel<<<nb, 256, 0, stream>>>(scratch, aggr, n_nodes, nw);

    node_kernel<<<nb, 256, 0, stream>>>(x, aggr,
        o_w1, o_b1, o_w2, o_b2, o_w3, o_b3, nodef, n_nodes);

    edge_kernel<false><<<eb, 256, 0, stream>>>(nodef, ei, (const void*)emsg,
        r2_w1, r2_b1, r2_w2, r2_b2, r2_w3, r2_b3,
        nullptr, (float*)d_out, n_edges);
}